// Round 9
// baseline (990.306 us; speedup 1.0000x reference)
//
#include <hip/hip_runtime.h>

#define NN 100000
#define EE 1600000
#define DD 128
#define NL 3
#define NQ 3
#define KK 16
#define ROWS_PER_FBLOCK 100
#define FUSED_BLOCKS (NN / ROWS_PER_FBLOCK)      // 1000
#define LPART_COUNT (NL * FUSED_BLOCKS)

// permuted codebook layout (words): entry k, dim = sq*32 + i*4 + d  lives at
//   (layer*NQ + q)*QSTRIDE + i*ISTRIDE + k*16 + sq*4 + d
// so the dot-read for lane l (= kq*4+sq) is a linear float4 at i*ISTRIDE + l*4.
#define ISTRIDE 260                  // 64 lanes*4 words + 4 pad (bank shear)
#define QSTRIDE (8 * ISTRIDE)        // 2080 words per (layer,q)
#define LAYER_CBN (NQ * QSTRIDE)     // 6240 words per layer
// resid layout (words): dim = s*32 + j -> s*RSTRIDE + j
#define RSTRIDE 36
#define RBUF 144                     // keeps rows 16B aligned

// ---- workspace layout (bytes) ----
// The padded deg/cursor arrays (atomic line-contention fix: one row per 64B
// line) alias the AGG region — they are dead before the first k_spmm runs.
static constexpr size_t OFF_AGG   = 0;          // N*D f32       = 51,200,000
static constexpr size_t OFF_DEGP  = 0;          // N*16 i32      =  6,400,000 (aliases AGG)
static constexpr size_t OFF_CURP  = 6400000;    // N*16 i32      =  6,400,000 (aliases AGG)
static constexpr size_t OFF_CSR   = 51200000;   // E   i32       =  6,400,000
static constexpr size_t OFF_CBN   = 57600000;   // 9*2080 f32    =     74,880
static constexpr size_t OFF_NORM  = 57904128;   // N   f32       =    400,000
static constexpr size_t OFF_RS    = 59104128;   // (N+1) i32     =    400,004
static constexpr size_t OFF_BSUM  = 59504640;   // 128 i32
static constexpr size_t OFF_LPART = 59505152;   // NL*1000 f32
static constexpr size_t WS_NEEDED = 59805152;

// ---------- CSR build ----------
__global__ __launch_bounds__(256) void k_count(const int* __restrict__ erow,
                                               int* __restrict__ degp) {
    int e = blockIdx.x * 256 + threadIdx.x;
    if (e < EE) atomicAdd(&degp[erow[e] << 4], 1);
}

__global__ __launch_bounds__(1024) void k_scan1(const int* __restrict__ degp,
                                                int* __restrict__ rs,
                                                int* __restrict__ bsum) {
    __shared__ int s[1024];
    int tid = threadIdx.x;
    int idx = blockIdx.x * 1024 + tid;
    int v = (idx < NN) ? degp[idx << 4] : 0;
    s[tid] = v;
    __syncthreads();
    for (int o = 1; o < 1024; o <<= 1) {
        int t2 = s[tid];
        if (tid >= o) t2 += s[tid - o];
        __syncthreads();
        s[tid] = t2;
        __syncthreads();
    }
    if (idx < NN) rs[idx] = s[tid] - v;       // exclusive
    if (tid == 1023) bsum[blockIdx.x] = s[1023];
}

__global__ __launch_bounds__(128) void k_scan2(int* __restrict__ bsum, int nb) {
    __shared__ int s[128];
    int tid = threadIdx.x;
    int v = (tid < nb) ? bsum[tid] : 0;
    s[tid] = v;
    __syncthreads();
    for (int o = 1; o < 128; o <<= 1) {
        int t2 = s[tid];
        if (tid >= o) t2 += s[tid - o];
        __syncthreads();
        s[tid] = t2;
        __syncthreads();
    }
    if (tid < nb) bsum[tid] = s[tid] - v;     // exclusive
}

__global__ __launch_bounds__(1024) void k_scan3(const int* __restrict__ degp,
                                                int* __restrict__ rs,
                                                const int* __restrict__ bsum,
                                                float* __restrict__ normf) {
    int idx = blockIdx.x * 1024 + threadIdx.x;
    if (idx < NN) {
        rs[idx] += bsum[blockIdx.x];
        normf[idx] = rsqrtf(1.0f + (float)degp[idx << 4]);
    }
    if (idx == 0) rs[NN] = EE;
}

__global__ __launch_bounds__(256) void k_fill(const int* __restrict__ erow,
                                              const int* __restrict__ ecol,
                                              const int* __restrict__ rs,
                                              int* __restrict__ cursorp,
                                              int* __restrict__ csr) {
    int e = blockIdx.x * 256 + threadIdx.x;
    if (e < EE) {
        int r = erow[e];
        int p = atomicAdd(&cursorp[r << 4], 1);
        csr[rs[r] + p] = ecol[e];
    }
}

// ---------- canonicalize neighbor order (determinism across replays) ----------
__global__ __launch_bounds__(256) void k_sortwave(const int* __restrict__ rs,
                                                  int* __restrict__ csr) {
    int wid = (blockIdx.x * 256 + threadIdx.x) >> 6;   // one wave per row
    int l = threadIdx.x & 63;
    if (wid >= NN) return;
    int s0 = rs[wid], e0 = rs[wid + 1];
    int deg = e0 - s0;
    if (deg <= 1) return;
    if (deg <= 64) {
        int v = (l < deg) ? csr[s0 + l] : 0x7fffffff;
        int rank = 0;
#pragma unroll 8
        for (int m = 0; m < 64; ++m) {
            int vm = __shfl(v, m);
            bool less = (vm < v) || (vm == v && m < l);
            rank += (m < deg && less) ? 1 : 0;
        }
        if (l < deg) csr[s0 + rank] = v;
    } else if (l == 0) {                    // vanishingly rare fallback
        for (int i = s0 + 1; i < e0; ++i) {
            int v = csr[i];
            int j = i - 1;
            while (j >= s0 && csr[j] > v) { csr[j + 1] = csr[j]; --j; }
            csr[j + 1] = v;
        }
    }
}

// ---------- codebook normalize -> permuted layout ----------
__global__ __launch_bounds__(128) void k_cbnorm(const float* __restrict__ cb,
                                                float* __restrict__ cbn) {
    __shared__ float s[128];
    int row = blockIdx.x;                 // (layer*NQ + q)*KK + k
    int tid = threadIdx.x;
    float v = cb[row * DD + tid];
    s[tid] = v * v;
    __syncthreads();
    for (int o = 64; o > 0; o >>= 1) {
        if (tid < o) s[tid] += s[tid + o];
        __syncthreads();
    }
    float inv = 1.0f / (sqrtf(s[0]) + 1e-12f);
    int lq = row >> 4;                    // layer*NQ + q  (0..8)
    int k  = row & 15;
    int sq = tid >> 5, ii = (tid >> 2) & 7, d = tid & 3;
    cbn[(size_t)lq * QSTRIDE + ii * ISTRIDE + k * 16 + sq * 4 + d] = v * inv;
}

// ---------- input linear: h = x @ w + b (LDS-staged w, 4x4 register tile) ----
__global__ __launch_bounds__(256) void k_gemm(const float* __restrict__ x,
                                              const float* __restrict__ w,
                                              const float* __restrict__ bias,
                                              float* __restrict__ h) {
    __shared__ float wls[64][DD];   // 32 KiB (one k-chunk of w)
    __shared__ float xs[32][DD];    // 16 KiB
    int tid = threadIdx.x;
    int rbase = blockIdx.x * 32;
    int cg = tid & 31;              // col group (4 cols)
    int rg = tid >> 5;              // row group (4 rows)

#pragma unroll
    for (int p = 0; p < 4; ++p) {   // stage x tile: 32x128
        int i = p * 256 + tid;
        int r = i >> 5, c = (i & 31) * 4;
        *(float4*)&xs[r][c] = *(const float4*)&x[(size_t)(rbase + r) * DD + c];
    }

    float4 acc[4];
#pragma unroll
    for (int i = 0; i < 4; ++i) acc[i] = make_float4(0.f, 0.f, 0.f, 0.f);

    for (int chunk = 0; chunk < 2; ++chunk) {
        __syncthreads();
#pragma unroll
        for (int p = 0; p < 8; ++p) {   // stage w chunk: 64x128
            int i = p * 256 + tid;
            int kr = i >> 5, c = (i & 31) * 4;
            *(float4*)&wls[kr][c] = *(const float4*)&w[(size_t)(chunk * 64 + kr) * DD + c];
        }
        __syncthreads();
#pragma unroll 4
        for (int kk = 0; kk < 64; ++kk) {
            float4 wv = *(const float4*)&wls[kk][cg * 4];
            int k = chunk * 64 + kk;
#pragma unroll
            for (int i = 0; i < 4; ++i) {
                float xv = xs[rg * 4 + i][k];
                acc[i].x += xv * wv.x; acc[i].y += xv * wv.y;
                acc[i].z += xv * wv.z; acc[i].w += xv * wv.w;
            }
        }
    }

    float4 bv = *(const float4*)&bias[cg * 4];
#pragma unroll
    for (int i = 0; i < 4; ++i) {
        float4 o;
        o.x = acc[i].x + bv.x; o.y = acc[i].y + bv.y;
        o.z = acc[i].z + bv.z; o.w = acc[i].w + bv.w;
        *(float4*)&h[(size_t)(rbase + rg * 4 + i) * DD + cg * 4] = o;
    }
}

// ---------- SpMM: agg[r] = sum_{c in neigh(r)} norm[c]*h[c] ----------
// 32 lanes per row (float4 each), 8 rows per 256-block, unroll-by-16 MLP.
// Per-component chains: ascending j, one fma per term -> bit-identical agg.
__global__ __launch_bounds__(256) void k_spmm(const float* __restrict__ h,
                                              const float* __restrict__ normf,
                                              const int* __restrict__ rs,
                                              const int* __restrict__ csr,
                                              float* __restrict__ agg) {
    int lane = threadIdx.x & 31;
    int slot = threadIdx.x >> 5;
    int r = blockIdx.x * 8 + slot;
    int s0 = rs[r], e0 = rs[r + 1];
    int off = lane << 2;

    float ax = 0.f, ay = 0.f, az = 0.f, aw = 0.f;
    int j = s0;
    for (; j + 16 <= e0; j += 16) {
        int c[16]; float n[16]; float4 v[16];
#pragma unroll
        for (int u = 0; u < 16; ++u) c[u] = csr[j + u];
#pragma unroll
        for (int u = 0; u < 16; ++u) n[u] = normf[c[u]];
#pragma unroll
        for (int u = 0; u < 16; ++u) v[u] = *(const float4*)&h[(size_t)c[u] * DD + off];
#pragma unroll
        for (int u = 0; u < 16; ++u) {
            ax += n[u] * v[u].x; ay += n[u] * v[u].y;
            az += n[u] * v[u].z; aw += n[u] * v[u].w;
        }
    }
    for (; j + 8 <= e0; j += 8) {
        int c[8]; float n[8]; float4 v[8];
#pragma unroll
        for (int u = 0; u < 8; ++u) c[u] = csr[j + u];
#pragma unroll
        for (int u = 0; u < 8; ++u) n[u] = normf[c[u]];
#pragma unroll
        for (int u = 0; u < 8; ++u) v[u] = *(const float4*)&h[(size_t)c[u] * DD + off];
#pragma unroll
        for (int u = 0; u < 8; ++u) {
            ax += n[u] * v[u].x; ay += n[u] * v[u].y;
            az += n[u] * v[u].z; aw += n[u] * v[u].w;
        }
    }
    for (; j + 4 <= e0; j += 4) {
        int c[4]; float n[4]; float4 v[4];
#pragma unroll
        for (int u = 0; u < 4; ++u) c[u] = csr[j + u];
#pragma unroll
        for (int u = 0; u < 4; ++u) n[u] = normf[c[u]];
#pragma unroll
        for (int u = 0; u < 4; ++u) v[u] = *(const float4*)&h[(size_t)c[u] * DD + off];
#pragma unroll
        for (int u = 0; u < 4; ++u) {
            ax += n[u] * v[u].x; ay += n[u] * v[u].y;
            az += n[u] * v[u].z; aw += n[u] * v[u].w;
        }
    }
    for (; j < e0; ++j) {
        int c = csr[j];
        float ns = normf[c];
        float4 v = *(const float4*)&h[(size_t)c * DD + off];
        ax += ns * v.x;
        ay += ns * v.y;
        az += ns * v.z;
        aw += ns * v.w;
    }
    float4 o = {ax, ay, az, aw};
    *(float4*)&agg[(size_t)r * DD + off] = o;
}

// ---------- fused: x1 = norm*(agg + norm*h); residual VQ; h += x1 ----------
// The resid exchange is wave-private (resid_s[w]); waves share nothing inside
// the row loop, so it runs wave-synchronously with NO cross-wave barriers.
__global__ __launch_bounds__(256) void k_fused(const float* __restrict__ agg,
                                               float* __restrict__ h,
                                               const float* __restrict__ normf,
                                               const float* __restrict__ cbn_layer,
                                               float* __restrict__ idsf,
                                               float* __restrict__ lpart,
                                               int layer) {
    __shared__ float cb_s[LAYER_CBN];        // 24,960 B (permuted layout)
    __shared__ float resid_s[4][RBUF];       // padded resid (stride 36/slice)
    __shared__ float wsum[4];
    int tid = threadIdx.x;

    {   // linear copy: global cbn is already in the permuted layout
        const float4* src = (const float4*)cbn_layer;
        float4* dst = (float4*)cb_s;
        for (int t = tid; t < LAYER_CBN / 4; t += 256) dst[t] = src[t];
    }
    __syncthreads();

    int w = tid >> 6;      // wave id
    int l = tid & 63;      // lane
    int rwrd = (l >> 4) * RSTRIDE + ((2 * l) & 31);           // resid write word
    int sq = l & 3;                                            // resid read slice
    int cb2 = ((l >> 1) & 7) * ISTRIDE + (l >> 4) * 4 + 2 * (l & 1); // cb[?][2l] word
    float lsum = 0.f;

    for (int it = 0; it < ROWS_PER_FBLOCK / 4; ++it) {
        int r = blockIdx.x * ROWS_PER_FBLOCK + it * 4 + w;

        float nr = normf[r];
        float2 hv = *(const float2*)&h[(size_t)r * DD + 2 * l];
        float2 av = *(const float2*)&agg[(size_t)r * DD + 2 * l];
        float x0 = nr * (av.x + nr * hv.x);
        float x1 = nr * (av.y + nr * hv.y);
        float r0 = x0, r1 = x1;

        for (int q = 0; q < NQ; ++q) {
            *(float2*)&resid_s[w][rwrd] = make_float2(r0, r1);
            // wave-synchronous: same-wave ds_write -> ds_read, compiler-ordered

            const float* cbq = &cb_s[q * QSTRIDE];
            const float* rsd = resid_s[w];
            float pd = 0.f;
#pragma unroll
            for (int i = 0; i < 8; ++i) {
                float4 cv = *(const float4*)&cbq[i * ISTRIDE + l * 4];
                float4 rv = *(const float4*)&rsd[sq * RSTRIDE + i * 4];
                pd += cv.x * rv.x + cv.y * rv.y + cv.z * rv.z + cv.w * rv.w;
            }
            pd += __shfl_xor(pd, 1);
            pd += __shfl_xor(pd, 2);   // full dot(resid, cbn[kq]) in each quad

            float best = pd;
            int bk = l >> 2;
            for (int m = 4; m < 64; m <<= 1) {
                float ov = __shfl_xor(best, m);
                int oi = __shfl_xor(bk, m);
                if (ov > best || (ov == best && oi < bk)) { best = ov; bk = oi; }
            }
            // bk = argmax (min index on tie), agreed by all lanes

            float2 cv2 = *(const float2*)&cb_s[q * QSTRIDE + bk * 16 + cb2];
            r0 -= cv2.x;
            r1 -= cv2.y;
            lsum += r0 * r0 + r1 * r1;

            if (l == 0) idsf[(size_t)r * (NL * NQ) + layer * NQ + q] = (float)bk;
        }

        *(float2*)&h[(size_t)r * DD + 2 * l] = make_float2(x0 + hv.x, x1 + hv.y);
    }

    // block loss partial (deterministic)
#pragma unroll
    for (int m = 1; m < 64; m <<= 1) lsum += __shfl_xor(lsum, m);
    if (l == 0) wsum[w] = lsum;
    __syncthreads();
    if (tid == 0) {
        float tot = wsum[0] + wsum[1] + wsum[2] + wsum[3];
        lpart[layer * FUSED_BLOCKS + blockIdx.x] = tot * (0.25f / (float)(NN * DD));
    }
}

__global__ __launch_bounds__(256) void k_loss_reduce(const float* __restrict__ part,
                                                     float* __restrict__ out_loss) {
    __shared__ float s[256];
    float a = 0.f;
    for (int i = threadIdx.x; i < LPART_COUNT; i += 256) a += part[i];
    s[threadIdx.x] = a;
    __syncthreads();
    for (int o = 128; o > 0; o >>= 1) {
        if (threadIdx.x < o) s[threadIdx.x] += s[threadIdx.x + o];
        __syncthreads();
    }
    if (threadIdx.x == 0) out_loss[0] = s[0];
}

extern "C" void kernel_launch(void* const* d_in, const int* in_sizes, int n_in,
                              void* d_out, int out_size, void* d_ws, size_t ws_size,
                              hipStream_t stream) {
    if (ws_size < WS_NEEDED) return;

    const float* x    = (const float*)d_in[0];
    const float* w_in = (const float*)d_in[1];
    const float* b_in = (const float*)d_in[2];
    const float* cbs  = (const float*)d_in[3];
    const int*   erow = (const int*)d_in[4];
    const int*   ecol = (const int*)d_in[5];

    float* out  = (float*)d_out;
    float* hbuf = out;                                   // [N][D] working h = output 0
    float* loss = out + (size_t)NN * DD;                 // scalar output 1
    float* idsf = out + (size_t)NN * DD + 1;             // [N][9] output 2 (as float)

    char* ws = (char*)d_ws;
    float* agg     = (float*)(ws + OFF_AGG);
    int*   degp    = (int*)(ws + OFF_DEGP);              // aliases agg (dead before spmm)
    int*   cursorp = (int*)(ws + OFF_CURP);              // aliases agg (dead before spmm)
    int*   csr     = (int*)(ws + OFF_CSR);
    float* cbn     = (float*)(ws + OFF_CBN);
    float* normf   = (float*)(ws + OFF_NORM);
    int*   rs      = (int*)(ws + OFF_RS);
    int*   bsum    = (int*)(ws + OFF_BSUM);
    float* lpart   = (float*)(ws + OFF_LPART);

    // zero padded deg + cursor (12.8 MB, contiguous at front of agg region)
    hipMemsetAsync(ws + OFF_DEGP, 0, 12800000, stream);

    const int NB_E  = (EE + 255) / 256;      // 6250
    const int NB_SC = (NN + 1023) / 1024;    // 98
    const int NB_W  = (NN + 3) / 4;          // 25000 (4 waves/block)

    k_count<<<NB_E, 256, 0, stream>>>(erow, degp);
    k_scan1<<<NB_SC, 1024, 0, stream>>>(degp, rs, bsum);
    k_scan2<<<1, 128, 0, stream>>>(bsum, NB_SC);
    k_scan3<<<NB_SC, 1024, 0, stream>>>(degp, rs, bsum, normf);
    k_fill<<<NB_E, 256, 0, stream>>>(erow, ecol, rs, cursorp, csr);
    k_sortwave<<<NB_W, 256, 0, stream>>>(rs, csr);

    k_cbnorm<<<NL * NQ * KK, 128, 0, stream>>>(cbs, cbn);
    k_gemm<<<NN / 32, 256, 0, stream>>>(x, w_in, b_in, hbuf);

    for (int layer = 0; layer < NL; ++layer) {
        k_spmm<<<NN / 8, 256, 0, stream>>>(hbuf, normf, rs, csr, agg);
        k_fused<<<FUSED_BLOCKS, 256, 0, stream>>>(agg, hbuf, normf,
                                                  cbn + (size_t)layer * LAYER_CBN,
                                                  idsf, lpart, layer);
    }

    k_loss_reduce<<<1, 256, 0, stream>>>(lpart, loss);
}

// Round 10
// 947.897 us; speedup vs baseline: 1.0447x; 1.0447x over previous
//
#include <hip/hip_runtime.h>

#define NN 100000
#define EE 1600000
#define DD 128
#define NL 3
#define NQ 3
#define KK 16
#define ROWS_PER_FBLOCK 32
#define FUSED_BLOCKS (NN / ROWS_PER_FBLOCK)      // 3125
#define LPART_COUNT (NL * FUSED_BLOCKS)

// permuted codebook layout (words): entry k, dim = sq*32 + i*4 + d  lives at
//   (layer*NQ + q)*QSTRIDE + i*ISTRIDE + k*16 + sq*4 + d
// so the dot-read for lane l (= kq*4+sq) is a linear float4 at i*ISTRIDE + l*4.
#define ISTRIDE 260                  // 64 lanes*4 words + 4 pad (bank shear)
#define QSTRIDE (8 * ISTRIDE)        // 2080 words per (layer,q)
#define LAYER_CBN (NQ * QSTRIDE)     // 6240 words per layer
// resid layout (words): dim = s*32 + j -> s*RSTRIDE + j
#define RSTRIDE 36
#define RBUF 144                     // keeps rows 16B aligned

// ---- workspace layout (bytes) ----
// The padded deg/cursor arrays (atomic line-contention fix: one row per 64B
// line) alias the AGG region — they are dead before the first k_spmm runs.
static constexpr size_t OFF_AGG   = 0;          // N*D f32       = 51,200,000
static constexpr size_t OFF_DEGP  = 0;          // N*16 i32      =  6,400,000 (aliases AGG)
static constexpr size_t OFF_CURP  = 6400000;    // N*16 i32      =  6,400,000 (aliases AGG)
static constexpr size_t OFF_CSR   = 51200000;   // E   i32       =  6,400,000
static constexpr size_t OFF_CBN   = 57600000;   // 9*2080 f32    =     74,880
static constexpr size_t OFF_NORM  = 57904128;   // N   f32       =    400,000
static constexpr size_t OFF_RS    = 59104128;   // (N+1) i32     =    400,004
static constexpr size_t OFF_BSUM  = 59504640;   // 128 i32
static constexpr size_t OFF_LPART = 59505152;   // NL*3125 f32
static constexpr size_t WS_NEEDED = 59805152;

// ---------- CSR build ----------
__global__ __launch_bounds__(256) void k_count(const int* __restrict__ erow,
                                               int* __restrict__ degp) {
    int e = blockIdx.x * 256 + threadIdx.x;
    if (e < EE) atomicAdd(&degp[erow[e] << 4], 1);
}

__global__ __launch_bounds__(1024) void k_scan1(const int* __restrict__ degp,
                                                int* __restrict__ rs,
                                                int* __restrict__ bsum) {
    __shared__ int s[1024];
    int tid = threadIdx.x;
    int idx = blockIdx.x * 1024 + tid;
    int v = (idx < NN) ? degp[idx << 4] : 0;
    s[tid] = v;
    __syncthreads();
    for (int o = 1; o < 1024; o <<= 1) {
        int t2 = s[tid];
        if (tid >= o) t2 += s[tid - o];
        __syncthreads();
        s[tid] = t2;
        __syncthreads();
    }
    if (idx < NN) rs[idx] = s[tid] - v;       // exclusive
    if (tid == 1023) bsum[blockIdx.x] = s[1023];
}

__global__ __launch_bounds__(128) void k_scan2(int* __restrict__ bsum, int nb) {
    __shared__ int s[128];
    int tid = threadIdx.x;
    int v = (tid < nb) ? bsum[tid] : 0;
    s[tid] = v;
    __syncthreads();
    for (int o = 1; o < 128; o <<= 1) {
        int t2 = s[tid];
        if (tid >= o) t2 += s[tid - o];
        __syncthreads();
        s[tid] = t2;
        __syncthreads();
    }
    if (tid < nb) bsum[tid] = s[tid] - v;     // exclusive
}

__global__ __launch_bounds__(1024) void k_scan3(const int* __restrict__ degp,
                                                int* __restrict__ rs,
                                                const int* __restrict__ bsum,
                                                float* __restrict__ normf) {
    int idx = blockIdx.x * 1024 + threadIdx.x;
    if (idx < NN) {
        rs[idx] += bsum[blockIdx.x];
        normf[idx] = rsqrtf(1.0f + (float)degp[idx << 4]);
    }
    if (idx == 0) rs[NN] = EE;
}

__global__ __launch_bounds__(256) void k_fill(const int* __restrict__ erow,
                                              const int* __restrict__ ecol,
                                              const int* __restrict__ rs,
                                              int* __restrict__ cursorp,
                                              int* __restrict__ csr) {
    int e = blockIdx.x * 256 + threadIdx.x;
    if (e < EE) {
        int r = erow[e];
        int p = atomicAdd(&cursorp[r << 4], 1);
        csr[rs[r] + p] = ecol[e];
    }
}

// ---------- canonicalize neighbor order (determinism across replays) ----------
__global__ __launch_bounds__(256) void k_sortwave(const int* __restrict__ rs,
                                                  int* __restrict__ csr) {
    int wid = (blockIdx.x * 256 + threadIdx.x) >> 6;   // one wave per row
    int l = threadIdx.x & 63;
    if (wid >= NN) return;
    int s0 = rs[wid], e0 = rs[wid + 1];
    int deg = e0 - s0;
    if (deg <= 1) return;
    if (deg <= 64) {
        int v = (l < deg) ? csr[s0 + l] : 0x7fffffff;
        int rank = 0;
#pragma unroll 8
        for (int m = 0; m < 64; ++m) {
            int vm = __shfl(v, m);
            bool less = (vm < v) || (vm == v && m < l);
            rank += (m < deg && less) ? 1 : 0;
        }
        if (l < deg) csr[s0 + rank] = v;
    } else if (l == 0) {                    // vanishingly rare fallback
        for (int i = s0 + 1; i < e0; ++i) {
            int v = csr[i];
            int j = i - 1;
            while (j >= s0 && csr[j] > v) { csr[j + 1] = csr[j]; --j; }
            csr[j + 1] = v;
        }
    }
}

// ---------- codebook normalize -> permuted layout ----------
__global__ __launch_bounds__(128) void k_cbnorm(const float* __restrict__ cb,
                                                float* __restrict__ cbn) {
    __shared__ float s[128];
    int row = blockIdx.x;                 // (layer*NQ + q)*KK + k
    int tid = threadIdx.x;
    float v = cb[row * DD + tid];
    s[tid] = v * v;
    __syncthreads();
    for (int o = 64; o > 0; o >>= 1) {
        if (tid < o) s[tid] += s[tid + o];
        __syncthreads();
    }
    float inv = 1.0f / (sqrtf(s[0]) + 1e-12f);
    int lq = row >> 4;                    // layer*NQ + q  (0..8)
    int k  = row & 15;
    int sq = tid >> 5, ii = (tid >> 2) & 7, d = tid & 3;
    cbn[(size_t)lq * QSTRIDE + ii * ISTRIDE + k * 16 + sq * 4 + d] = v * inv;
}

// ---------- input linear: h = x @ w + b (LDS-staged w, 4x4 register tile) ----
__global__ __launch_bounds__(256) void k_gemm(const float* __restrict__ x,
                                              const float* __restrict__ w,
                                              const float* __restrict__ bias,
                                              float* __restrict__ h) {
    __shared__ float wls[64][DD];   // 32 KiB (one k-chunk of w)
    __shared__ float xs[32][DD];    // 16 KiB
    int tid = threadIdx.x;
    int rbase = blockIdx.x * 32;
    int cg = tid & 31;              // col group (4 cols)
    int rg = tid >> 5;              // row group (4 rows)

#pragma unroll
    for (int p = 0; p < 4; ++p) {   // stage x tile: 32x128
        int i = p * 256 + tid;
        int r = i >> 5, c = (i & 31) * 4;
        *(float4*)&xs[r][c] = *(const float4*)&x[(size_t)(rbase + r) * DD + c];
    }

    float4 acc[4];
#pragma unroll
    for (int i = 0; i < 4; ++i) acc[i] = make_float4(0.f, 0.f, 0.f, 0.f);

    for (int chunk = 0; chunk < 2; ++chunk) {
        __syncthreads();
#pragma unroll
        for (int p = 0; p < 8; ++p) {   // stage w chunk: 64x128
            int i = p * 256 + tid;
            int kr = i >> 5, c = (i & 31) * 4;
            *(float4*)&wls[kr][c] = *(const float4*)&w[(size_t)(chunk * 64 + kr) * DD + c];
        }
        __syncthreads();
#pragma unroll 4
        for (int kk = 0; kk < 64; ++kk) {
            float4 wv = *(const float4*)&wls[kk][cg * 4];
            int k = chunk * 64 + kk;
#pragma unroll
            for (int i = 0; i < 4; ++i) {
                float xv = xs[rg * 4 + i][k];
                acc[i].x += xv * wv.x; acc[i].y += xv * wv.y;
                acc[i].z += xv * wv.z; acc[i].w += xv * wv.w;
            }
        }
    }

    float4 bv = *(const float4*)&bias[cg * 4];
#pragma unroll
    for (int i = 0; i < 4; ++i) {
        float4 o;
        o.x = acc[i].x + bv.x; o.y = acc[i].y + bv.y;
        o.z = acc[i].z + bv.z; o.w = acc[i].w + bv.w;
        *(float4*)&h[(size_t)(rbase + rg * 4 + i) * DD + cg * 4] = o;
    }
}

// ---------- SpMM: agg[r] = sum_{c in neigh(r)} norm[c]*h[c] ----------
// 32 lanes per row (float4 each), 8 rows per 256-block, unroll-by-16 MLP.
// Per-component chains: ascending j, one fma per term -> bit-identical agg.
__global__ __launch_bounds__(256) void k_spmm(const float* __restrict__ h,
                                              const float* __restrict__ normf,
                                              const int* __restrict__ rs,
                                              const int* __restrict__ csr,
                                              float* __restrict__ agg) {
    int lane = threadIdx.x & 31;
    int slot = threadIdx.x >> 5;
    int r = blockIdx.x * 8 + slot;
    int s0 = rs[r], e0 = rs[r + 1];
    int off = lane << 2;

    float ax = 0.f, ay = 0.f, az = 0.f, aw = 0.f;
    int j = s0;
    for (; j + 16 <= e0; j += 16) {
        int c[16]; float n[16]; float4 v[16];
#pragma unroll
        for (int u = 0; u < 16; ++u) c[u] = csr[j + u];
#pragma unroll
        for (int u = 0; u < 16; ++u) n[u] = normf[c[u]];
#pragma unroll
        for (int u = 0; u < 16; ++u) v[u] = *(const float4*)&h[(size_t)c[u] * DD + off];
#pragma unroll
        for (int u = 0; u < 16; ++u) {
            ax += n[u] * v[u].x; ay += n[u] * v[u].y;
            az += n[u] * v[u].z; aw += n[u] * v[u].w;
        }
    }
    for (; j + 8 <= e0; j += 8) {
        int c[8]; float n[8]; float4 v[8];
#pragma unroll
        for (int u = 0; u < 8; ++u) c[u] = csr[j + u];
#pragma unroll
        for (int u = 0; u < 8; ++u) n[u] = normf[c[u]];
#pragma unroll
        for (int u = 0; u < 8; ++u) v[u] = *(const float4*)&h[(size_t)c[u] * DD + off];
#pragma unroll
        for (int u = 0; u < 8; ++u) {
            ax += n[u] * v[u].x; ay += n[u] * v[u].y;
            az += n[u] * v[u].z; aw += n[u] * v[u].w;
        }
    }
    for (; j + 4 <= e0; j += 4) {
        int c[4]; float n[4]; float4 v[4];
#pragma unroll
        for (int u = 0; u < 4; ++u) c[u] = csr[j + u];
#pragma unroll
        for (int u = 0; u < 4; ++u) n[u] = normf[c[u]];
#pragma unroll
        for (int u = 0; u < 4; ++u) v[u] = *(const float4*)&h[(size_t)c[u] * DD + off];
#pragma unroll
        for (int u = 0; u < 4; ++u) {
            ax += n[u] * v[u].x; ay += n[u] * v[u].y;
            az += n[u] * v[u].z; aw += n[u] * v[u].w;
        }
    }
    for (; j < e0; ++j) {
        int c = csr[j];
        float ns = normf[c];
        float4 v = *(const float4*)&h[(size_t)c * DD + off];
        ax += ns * v.x;
        ay += ns * v.y;
        az += ns * v.z;
        aw += ns * v.w;
    }
    float4 o = {ax, ay, az, aw};
    *(float4*)&agg[(size_t)r * DD + off] = o;
}

// ---------- fused: x1 = norm*(agg + norm*h); residual VQ; h += x1 ----------
// The resid exchange is wave-private (resid_s[w]); waves share nothing inside
// the row loop, so it runs wave-synchronously with NO cross-wave barriers.
// (Barrier-free exchange validated in the R9 run: all outputs + replay
// tripwires passed.)
__global__ __launch_bounds__(256) void k_fused(const float* __restrict__ agg,
                                               float* __restrict__ h,
                                               const float* __restrict__ normf,
                                               const float* __restrict__ cbn_layer,
                                               float* __restrict__ idsf,
                                               float* __restrict__ lpart,
                                               int layer) {
    __shared__ float cb_s[LAYER_CBN];        // 24,960 B (permuted layout)
    __shared__ float resid_s[4][RBUF];       // padded resid (stride 36/slice)
    __shared__ float wsum[4];
    int tid = threadIdx.x;

    {   // linear copy: global cbn is already in the permuted layout
        const float4* src = (const float4*)cbn_layer;
        float4* dst = (float4*)cb_s;
        for (int t = tid; t < LAYER_CBN / 4; t += 256) dst[t] = src[t];
    }
    __syncthreads();

    int w = tid >> 6;      // wave id
    int l = tid & 63;      // lane
    int rwrd = (l >> 4) * RSTRIDE + ((2 * l) & 31);           // resid write word
    int sq = l & 3;                                            // resid read slice
    int cb2 = ((l >> 1) & 7) * ISTRIDE + (l >> 4) * 4 + 2 * (l & 1); // cb[?][2l] word
    float lsum = 0.f;

    for (int it = 0; it < ROWS_PER_FBLOCK / 4; ++it) {
        int r = blockIdx.x * ROWS_PER_FBLOCK + it * 4 + w;

        float nr = normf[r];
        float2 hv = *(const float2*)&h[(size_t)r * DD + 2 * l];
        float2 av = *(const float2*)&agg[(size_t)r * DD + 2 * l];
        float x0 = nr * (av.x + nr * hv.x);
        float x1 = nr * (av.y + nr * hv.y);
        float r0 = x0, r1 = x1;

        for (int q = 0; q < NQ; ++q) {
            *(float2*)&resid_s[w][rwrd] = make_float2(r0, r1);
            // wave-synchronous: same-wave ds_write -> ds_read, compiler-ordered

            const float* cbq = &cb_s[q * QSTRIDE];
            const float* rsd = resid_s[w];
            float pd = 0.f;
#pragma unroll
            for (int i = 0; i < 8; ++i) {
                float4 cv = *(const float4*)&cbq[i * ISTRIDE + l * 4];
                float4 rv = *(const float4*)&rsd[sq * RSTRIDE + i * 4];
                pd += cv.x * rv.x + cv.y * rv.y + cv.z * rv.z + cv.w * rv.w;
            }
            pd += __shfl_xor(pd, 1);
            pd += __shfl_xor(pd, 2);   // full dot(resid, cbn[kq]) in each quad

            float best = pd;
            int bk = l >> 2;
            for (int m = 4; m < 64; m <<= 1) {
                float ov = __shfl_xor(best, m);
                int oi = __shfl_xor(bk, m);
                if (ov > best || (ov == best && oi < bk)) { best = ov; bk = oi; }
            }
            // bk = argmax (min index on tie), agreed by all lanes

            float2 cv2 = *(const float2*)&cb_s[q * QSTRIDE + bk * 16 + cb2];
            r0 -= cv2.x;
            r1 -= cv2.y;
            lsum += r0 * r0 + r1 * r1;

            if (l == 0) idsf[(size_t)r * (NL * NQ) + layer * NQ + q] = (float)bk;
        }

        *(float2*)&h[(size_t)r * DD + 2 * l] = make_float2(x0 + hv.x, x1 + hv.y);
    }

    // block loss partial (deterministic)
#pragma unroll
    for (int m = 1; m < 64; m <<= 1) lsum += __shfl_xor(lsum, m);
    if (l == 0) wsum[w] = lsum;
    __syncthreads();
    if (tid == 0) {
        float tot = wsum[0] + wsum[1] + wsum[2] + wsum[3];
        lpart[layer * FUSED_BLOCKS + blockIdx.x] = tot * (0.25f / (float)(NN * DD));
    }
}

__global__ __launch_bounds__(256) void k_loss_reduce(const float* __restrict__ part,
                                                     float* __restrict__ out_loss) {
    __shared__ float s[256];
    float a = 0.f;
    for (int i = threadIdx.x; i < LPART_COUNT; i += 256) a += part[i];
    s[threadIdx.x] = a;
    __syncthreads();
    for (int o = 128; o > 0; o >>= 1) {
        if (threadIdx.x < o) s[threadIdx.x] += s[threadIdx.x + o];
        __syncthreads();
    }
    if (threadIdx.x == 0) out_loss[0] = s[0];
}

extern "C" void kernel_launch(void* const* d_in, const int* in_sizes, int n_in,
                              void* d_out, int out_size, void* d_ws, size_t ws_size,
                              hipStream_t stream) {
    if (ws_size < WS_NEEDED) return;

    const float* x    = (const float*)d_in[0];
    const float* w_in = (const float*)d_in[1];
    const float* b_in = (const float*)d_in[2];
    const float* cbs  = (const float*)d_in[3];
    const int*   erow = (const int*)d_in[4];
    const int*   ecol = (const int*)d_in[5];

    float* out  = (float*)d_out;
    float* hbuf = out;                                   // [N][D] working h = output 0
    float* loss = out + (size_t)NN * DD;                 // scalar output 1
    float* idsf = out + (size_t)NN * DD + 1;             // [N][9] output 2 (as float)

    char* ws = (char*)d_ws;
    float* agg     = (float*)(ws + OFF_AGG);
    int*   degp    = (int*)(ws + OFF_DEGP);              // aliases agg (dead before spmm)
    int*   cursorp = (int*)(ws + OFF_CURP);              // aliases agg (dead before spmm)
    int*   csr     = (int*)(ws + OFF_CSR);
    float* cbn     = (float*)(ws + OFF_CBN);
    float* normf   = (float*)(ws + OFF_NORM);
    int*   rs      = (int*)(ws + OFF_RS);
    int*   bsum    = (int*)(ws + OFF_BSUM);
    float* lpart   = (float*)(ws + OFF_LPART);

    // zero padded deg + cursor (12.8 MB, contiguous at front of agg region)
    hipMemsetAsync(ws + OFF_DEGP, 0, 12800000, stream);

    const int NB_E  = (EE + 255) / 256;      // 6250
    const int NB_SC = (NN + 1023) / 1024;    // 98
    const int NB_W  = (NN + 3) / 4;          // 25000 (4 waves/block)

    k_count<<<NB_E, 256, 0, stream>>>(erow, degp);
    k_scan1<<<NB_SC, 1024, 0, stream>>>(degp, rs, bsum);
    k_scan2<<<1, 128, 0, stream>>>(bsum, NB_SC);
    k_scan3<<<NB_SC, 1024, 0, stream>>>(degp, rs, bsum, normf);
    k_fill<<<NB_E, 256, 0, stream>>>(erow, ecol, rs, cursorp, csr);
    k_sortwave<<<NB_W, 256, 0, stream>>>(rs, csr);

    k_cbnorm<<<NL * NQ * KK, 128, 0, stream>>>(cbs, cbn);
    k_gemm<<<NN / 32, 256, 0, stream>>>(x, w_in, b_in, hbuf);

    for (int layer = 0; layer < NL; ++layer) {
        k_spmm<<<NN / 8, 256, 0, stream>>>(hbuf, normf, rs, csr, agg);
        k_fused<<<FUSED_BLOCKS, 256, 0, stream>>>(agg, hbuf, normf,
                                                  cbn + (size_t)layer * LAYER_CBN,
                                                  idsf, lpart, layer);
    }

    k_loss_reduce<<<1, 256, 0, stream>>>(lpart, loss);
}

// Round 11
// 927.977 us; speedup vs baseline: 1.0672x; 1.0215x over previous
//
#include <hip/hip_runtime.h>

#define NN 100000
#define EE 1600000
#define DD 128
#define NL 3
#define NQ 3
#define KK 16
#define ROWS_PER_FBLOCK 64
#define FUSED_BLOCKS ((NN + ROWS_PER_FBLOCK - 1) / ROWS_PER_FBLOCK)   // 1563
#define LPART_COUNT (NL * FUSED_BLOCKS)

// permuted codebook layout (words): entry k, dim = sq*32 + i*4 + d  lives at
//   (layer*NQ + q)*QSTRIDE + i*ISTRIDE + k*16 + sq*4 + d
// so the dot-read for lane l (= kq*4+sq) is a linear float4 at i*ISTRIDE + l*4.
#define ISTRIDE 260                  // 64 lanes*4 words + 4 pad (bank shear)
#define QSTRIDE (8 * ISTRIDE)        // 2080 words per (layer,q)
#define LAYER_CBN (NQ * QSTRIDE)     // 6240 words per layer
// resid layout (words): dim = s*32 + j -> s*RSTRIDE + j
#define RSTRIDE 36
#define RBUF 144                     // keeps rows 16B aligned

// ---- workspace layout (bytes) ----
// The padded deg/cursor arrays (atomic line-contention fix: one row per 64B
// line) alias the AGG region — they are dead before the first k_spmm runs.
static constexpr size_t OFF_AGG   = 0;          // N*D f32       = 51,200,000
static constexpr size_t OFF_DEGP  = 0;          // N*16 i32      =  6,400,000 (aliases AGG)
static constexpr size_t OFF_CURP  = 6400000;    // N*16 i32      =  6,400,000 (aliases AGG)
static constexpr size_t OFF_CSR   = 51200000;   // E   i32       =  6,400,000
static constexpr size_t OFF_CBN   = 57600000;   // 9*2080 f32    =     74,880
static constexpr size_t OFF_NORM  = 57904128;   // N   f32       =    400,000
static constexpr size_t OFF_RS    = 59104128;   // (N+1) i32     =    400,004
static constexpr size_t OFF_BSUM  = 59504640;   // 128 i32
static constexpr size_t OFF_LPART = 59505152;   // NL*1563 f32
static constexpr size_t WS_NEEDED = 59805152;

// ---------- CSR build ----------
__global__ __launch_bounds__(256) void k_count(const int* __restrict__ erow,
                                               int* __restrict__ degp) {
    int e = blockIdx.x * 256 + threadIdx.x;
    if (e < EE) atomicAdd(&degp[erow[e] << 4], 1);
}

__global__ __launch_bounds__(1024) void k_scan1(const int* __restrict__ degp,
                                                int* __restrict__ rs,
                                                int* __restrict__ bsum) {
    __shared__ int s[1024];
    int tid = threadIdx.x;
    int idx = blockIdx.x * 1024 + tid;
    int v = (idx < NN) ? degp[idx << 4] : 0;
    s[tid] = v;
    __syncthreads();
    for (int o = 1; o < 1024; o <<= 1) {
        int t2 = s[tid];
        if (tid >= o) t2 += s[tid - o];
        __syncthreads();
        s[tid] = t2;
        __syncthreads();
    }
    if (idx < NN) rs[idx] = s[tid] - v;       // exclusive
    if (tid == 1023) bsum[blockIdx.x] = s[1023];
}

__global__ __launch_bounds__(128) void k_scan2(int* __restrict__ bsum, int nb) {
    __shared__ int s[128];
    int tid = threadIdx.x;
    int v = (tid < nb) ? bsum[tid] : 0;
    s[tid] = v;
    __syncthreads();
    for (int o = 1; o < 128; o <<= 1) {
        int t2 = s[tid];
        if (tid >= o) t2 += s[tid - o];
        __syncthreads();
        s[tid] = t2;
        __syncthreads();
    }
    if (tid < nb) bsum[tid] = s[tid] - v;     // exclusive
}

__global__ __launch_bounds__(1024) void k_scan3(const int* __restrict__ degp,
                                                int* __restrict__ rs,
                                                const int* __restrict__ bsum,
                                                float* __restrict__ normf) {
    int idx = blockIdx.x * 1024 + threadIdx.x;
    if (idx < NN) {
        rs[idx] += bsum[blockIdx.x];
        normf[idx] = rsqrtf(1.0f + (float)degp[idx << 4]);
    }
    if (idx == 0) rs[NN] = EE;
}

__global__ __launch_bounds__(256) void k_fill(const int* __restrict__ erow,
                                              const int* __restrict__ ecol,
                                              const int* __restrict__ rs,
                                              int* __restrict__ cursorp,
                                              int* __restrict__ csr) {
    int e = blockIdx.x * 256 + threadIdx.x;
    if (e < EE) {
        int r = erow[e];
        int p = atomicAdd(&cursorp[r << 4], 1);
        // non-temporal: don't churn L2 lines on the random 4B scatter
        __builtin_nontemporal_store(ecol[e], &csr[rs[r] + p]);
    }
}

// ---------- canonicalize neighbor order (determinism across replays) ----------
__global__ __launch_bounds__(256) void k_sortwave(const int* __restrict__ rs,
                                                  int* __restrict__ csr) {
    int wid = (blockIdx.x * 256 + threadIdx.x) >> 6;   // one wave per row
    int l = threadIdx.x & 63;
    if (wid >= NN) return;
    int s0 = rs[wid], e0 = rs[wid + 1];
    int deg = e0 - s0;
    if (deg <= 1) return;
    if (deg <= 64) {
        int v = (l < deg) ? csr[s0 + l] : 0x7fffffff;
        int rank = 0;
#pragma unroll 8
        for (int m = 0; m < 64; ++m) {
            int vm = __shfl(v, m);
            bool less = (vm < v) || (vm == v && m < l);
            rank += (m < deg && less) ? 1 : 0;
        }
        if (l < deg) csr[s0 + rank] = v;
    } else if (l == 0) {                    // vanishingly rare fallback
        for (int i = s0 + 1; i < e0; ++i) {
            int v = csr[i];
            int j = i - 1;
            while (j >= s0 && csr[j] > v) { csr[j + 1] = csr[j]; --j; }
            csr[j + 1] = v;
        }
    }
}

// ---------- codebook normalize -> permuted layout ----------
__global__ __launch_bounds__(128) void k_cbnorm(const float* __restrict__ cb,
                                                float* __restrict__ cbn) {
    __shared__ float s[128];
    int row = blockIdx.x;                 // (layer*NQ + q)*KK + k
    int tid = threadIdx.x;
    float v = cb[row * DD + tid];
    s[tid] = v * v;
    __syncthreads();
    for (int o = 64; o > 0; o >>= 1) {
        if (tid < o) s[tid] += s[tid + o];
        __syncthreads();
    }
    float inv = 1.0f / (sqrtf(s[0]) + 1e-12f);
    int lq = row >> 4;                    // layer*NQ + q  (0..8)
    int k  = row & 15;
    int sq = tid >> 5, ii = (tid >> 2) & 7, d = tid & 3;
    cbn[(size_t)lq * QSTRIDE + ii * ISTRIDE + k * 16 + sq * 4 + d] = v * inv;
}

// ---------- input linear: h = x @ w + b (LDS-staged w, 4x4 register tile) ----
__global__ __launch_bounds__(256) void k_gemm(const float* __restrict__ x,
                                              const float* __restrict__ w,
                                              const float* __restrict__ bias,
                                              float* __restrict__ h) {
    __shared__ float wls[64][DD];   // 32 KiB (one k-chunk of w)
    __shared__ float xs[32][DD];    // 16 KiB
    int tid = threadIdx.x;
    int rbase = blockIdx.x * 32;
    int cg = tid & 31;              // col group (4 cols)
    int rg = tid >> 5;              // row group (4 rows)

#pragma unroll
    for (int p = 0; p < 4; ++p) {   // stage x tile: 32x128
        int i = p * 256 + tid;
        int r = i >> 5, c = (i & 31) * 4;
        *(float4*)&xs[r][c] = *(const float4*)&x[(size_t)(rbase + r) * DD + c];
    }

    float4 acc[4];
#pragma unroll
    for (int i = 0; i < 4; ++i) acc[i] = make_float4(0.f, 0.f, 0.f, 0.f);

    for (int chunk = 0; chunk < 2; ++chunk) {
        __syncthreads();
#pragma unroll
        for (int p = 0; p < 8; ++p) {   // stage w chunk: 64x128
            int i = p * 256 + tid;
            int kr = i >> 5, c = (i & 31) * 4;
            *(float4*)&wls[kr][c] = *(const float4*)&w[(size_t)(chunk * 64 + kr) * DD + c];
        }
        __syncthreads();
#pragma unroll 4
        for (int kk = 0; kk < 64; ++kk) {
            float4 wv = *(const float4*)&wls[kk][cg * 4];
            int k = chunk * 64 + kk;
#pragma unroll
            for (int i = 0; i < 4; ++i) {
                float xv = xs[rg * 4 + i][k];
                acc[i].x += xv * wv.x; acc[i].y += xv * wv.y;
                acc[i].z += xv * wv.z; acc[i].w += xv * wv.w;
            }
        }
    }

    float4 bv = *(const float4*)&bias[cg * 4];
#pragma unroll
    for (int i = 0; i < 4; ++i) {
        float4 o;
        o.x = acc[i].x + bv.x; o.y = acc[i].y + bv.y;
        o.z = acc[i].z + bv.z; o.w = acc[i].w + bv.w;
        *(float4*)&h[(size_t)(rbase + rg * 4 + i) * DD + cg * 4] = o;
    }
}

// ---------- SpMM: agg[r] = sum_{c in neigh(r)} norm[c]*h[c] ----------
// 32 lanes per row (float4 each), 8 rows per 256-block, unroll-by-16 MLP.
// Per-component chains: ascending j, one fma per term -> bit-identical agg.
__global__ __launch_bounds__(256) void k_spmm(const float* __restrict__ h,
                                              const float* __restrict__ normf,
                                              const int* __restrict__ rs,
                                              const int* __restrict__ csr,
                                              float* __restrict__ agg) {
    int lane = threadIdx.x & 31;
    int slot = threadIdx.x >> 5;
    int r = blockIdx.x * 8 + slot;
    int s0 = rs[r], e0 = rs[r + 1];
    int off = lane << 2;

    float ax = 0.f, ay = 0.f, az = 0.f, aw = 0.f;
    int j = s0;
    for (; j + 16 <= e0; j += 16) {
        int c[16]; float n[16]; float4 v[16];
#pragma unroll
        for (int u = 0; u < 16; ++u) c[u] = csr[j + u];
#pragma unroll
        for (int u = 0; u < 16; ++u) n[u] = normf[c[u]];
#pragma unroll
        for (int u = 0; u < 16; ++u) v[u] = *(const float4*)&h[(size_t)c[u] * DD + off];
#pragma unroll
        for (int u = 0; u < 16; ++u) {
            ax += n[u] * v[u].x; ay += n[u] * v[u].y;
            az += n[u] * v[u].z; aw += n[u] * v[u].w;
        }
    }
    for (; j + 8 <= e0; j += 8) {
        int c[8]; float n[8]; float4 v[8];
#pragma unroll
        for (int u = 0; u < 8; ++u) c[u] = csr[j + u];
#pragma unroll
        for (int u = 0; u < 8; ++u) n[u] = normf[c[u]];
#pragma unroll
        for (int u = 0; u < 8; ++u) v[u] = *(const float4*)&h[(size_t)c[u] * DD + off];
#pragma unroll
        for (int u = 0; u < 8; ++u) {
            ax += n[u] * v[u].x; ay += n[u] * v[u].y;
            az += n[u] * v[u].z; aw += n[u] * v[u].w;
        }
    }
    for (; j + 4 <= e0; j += 4) {
        int c[4]; float n[4]; float4 v[4];
#pragma unroll
        for (int u = 0; u < 4; ++u) c[u] = csr[j + u];
#pragma unroll
        for (int u = 0; u < 4; ++u) n[u] = normf[c[u]];
#pragma unroll
        for (int u = 0; u < 4; ++u) v[u] = *(const float4*)&h[(size_t)c[u] * DD + off];
#pragma unroll
        for (int u = 0; u < 4; ++u) {
            ax += n[u] * v[u].x; ay += n[u] * v[u].y;
            az += n[u] * v[u].z; aw += n[u] * v[u].w;
        }
    }
    for (; j < e0; ++j) {
        int c = csr[j];
        float ns = normf[c];
        float4 v = *(const float4*)&h[(size_t)c * DD + off];
        ax += ns * v.x;
        ay += ns * v.y;
        az += ns * v.z;
        aw += ns * v.w;
    }
    float4 o = {ax, ay, az, aw};
    *(float4*)&agg[(size_t)r * DD + off] = o;
}

// ---------- fused: x1 = norm*(agg + norm*h); residual VQ; h += x1 ----------
// 512 threads = 8 waves/block: same 27.6KB LDS now serves 8 waves -> the
// LDS-bound occupancy ceiling rises from 20 to 32 waves/CU, and codebook
// staging traffic halves. Per-row math/lane mapping unchanged (bit-identical
// h/ids). Resid exchange stays wave-private and barrier-free (validated R9/R10).
__global__ __launch_bounds__(512) void k_fused(const float* __restrict__ agg,
                                               float* __restrict__ h,
                                               const float* __restrict__ normf,
                                               const float* __restrict__ cbn_layer,
                                               float* __restrict__ idsf,
                                               float* __restrict__ lpart,
                                               int layer) {
    __shared__ float cb_s[LAYER_CBN];        // 24,960 B (permuted layout)
    __shared__ float resid_s[8][RBUF];       // padded resid (stride 36/slice)
    __shared__ float wsum[8];
    int tid = threadIdx.x;

    {   // linear copy: global cbn is already in the permuted layout
        const float4* src = (const float4*)cbn_layer;
        float4* dst = (float4*)cb_s;
        for (int t = tid; t < LAYER_CBN / 4; t += 512) dst[t] = src[t];
    }
    __syncthreads();

    int w = tid >> 6;      // wave id (0..7)
    int l = tid & 63;      // lane
    int rwrd = (l >> 4) * RSTRIDE + ((2 * l) & 31);           // resid write word
    int sq = l & 3;                                            // resid read slice
    int cb2 = ((l >> 1) & 7) * ISTRIDE + (l >> 4) * 4 + 2 * (l & 1); // cb[?][2l] word
    float lsum = 0.f;

    for (int it = 0; it < ROWS_PER_FBLOCK / 8; ++it) {
        int r = blockIdx.x * ROWS_PER_FBLOCK + it * 8 + w;
        if (r < NN) {                        // wave-uniform guard (tail block)
            float nr = normf[r];
            float2 hv = *(const float2*)&h[(size_t)r * DD + 2 * l];
            float2 av = *(const float2*)&agg[(size_t)r * DD + 2 * l];
            float x0 = nr * (av.x + nr * hv.x);
            float x1 = nr * (av.y + nr * hv.y);
            float r0 = x0, r1 = x1;

            for (int q = 0; q < NQ; ++q) {
                *(float2*)&resid_s[w][rwrd] = make_float2(r0, r1);
                // wave-synchronous: same-wave ds_write -> ds_read

                const float* cbq = &cb_s[q * QSTRIDE];
                const float* rsd = resid_s[w];
                float pd = 0.f;
#pragma unroll
                for (int i = 0; i < 8; ++i) {
                    float4 cv = *(const float4*)&cbq[i * ISTRIDE + l * 4];
                    float4 rv = *(const float4*)&rsd[sq * RSTRIDE + i * 4];
                    pd += cv.x * rv.x + cv.y * rv.y + cv.z * rv.z + cv.w * rv.w;
                }
                pd += __shfl_xor(pd, 1);
                pd += __shfl_xor(pd, 2);   // full dot(resid, cbn[kq]) in each quad

                float best = pd;
                int bk = l >> 2;
                for (int m = 4; m < 64; m <<= 1) {
                    float ov = __shfl_xor(best, m);
                    int oi = __shfl_xor(bk, m);
                    if (ov > best || (ov == best && oi < bk)) { best = ov; bk = oi; }
                }
                // bk = argmax (min index on tie), agreed by all lanes

                float2 cv2 = *(const float2*)&cb_s[q * QSTRIDE + bk * 16 + cb2];
                r0 -= cv2.x;
                r1 -= cv2.y;
                lsum += r0 * r0 + r1 * r1;

                if (l == 0) idsf[(size_t)r * (NL * NQ) + layer * NQ + q] = (float)bk;
            }

            *(float2*)&h[(size_t)r * DD + 2 * l] = make_float2(x0 + hv.x, x1 + hv.y);
        }
    }

    // block loss partial (deterministic)
#pragma unroll
    for (int m = 1; m < 64; m <<= 1) lsum += __shfl_xor(lsum, m);
    if (l == 0) wsum[w] = lsum;
    __syncthreads();
    if (tid == 0) {
        float tot = 0.f;
#pragma unroll
        for (int i = 0; i < 8; ++i) tot += wsum[i];
        lpart[layer * FUSED_BLOCKS + blockIdx.x] = tot * (0.25f / (float)(NN * DD));
    }
}

__global__ __launch_bounds__(256) void k_loss_reduce(const float* __restrict__ part,
                                                     float* __restrict__ out_loss) {
    __shared__ float s[256];
    float a = 0.f;
    for (int i = threadIdx.x; i < LPART_COUNT; i += 256) a += part[i];
    s[threadIdx.x] = a;
    __syncthreads();
    for (int o = 128; o > 0; o >>= 1) {
        if (threadIdx.x < o) s[threadIdx.x] += s[threadIdx.x + o];
        __syncthreads();
    }
    if (threadIdx.x == 0) out_loss[0] = s[0];
}

extern "C" void kernel_launch(void* const* d_in, const int* in_sizes, int n_in,
                              void* d_out, int out_size, void* d_ws, size_t ws_size,
                              hipStream_t stream) {
    if (ws_size < WS_NEEDED) return;

    const float* x    = (const float*)d_in[0];
    const float* w_in = (const float*)d_in[1];
    const float* b_in = (const float*)d_in[2];
    const float* cbs  = (const float*)d_in[3];
    const int*   erow = (const int*)d_in[4];
    const int*   ecol = (const int*)d_in[5];

    float* out  = (float*)d_out;
    float* hbuf = out;                                   // [N][D] working h = output 0
    float* loss = out + (size_t)NN * DD;                 // scalar output 1
    float* idsf = out + (size_t)NN * DD + 1;             // [N][9] output 2 (as float)

    char* ws = (char*)d_ws;
    float* agg     = (float*)(ws + OFF_AGG);
    int*   degp    = (int*)(ws + OFF_DEGP);              // aliases agg (dead before spmm)
    int*   cursorp = (int*)(ws + OFF_CURP);              // aliases agg (dead before spmm)
    int*   csr     = (int*)(ws + OFF_CSR);
    float* cbn     = (float*)(ws + OFF_CBN);
    float* normf   = (float*)(ws + OFF_NORM);
    int*   rs      = (int*)(ws + OFF_RS);
    int*   bsum    = (int*)(ws + OFF_BSUM);
    float* lpart   = (float*)(ws + OFF_LPART);

    // zero padded deg + cursor (12.8 MB, contiguous at front of agg region)
    hipMemsetAsync(ws + OFF_DEGP, 0, 12800000, stream);

    const int NB_E  = (EE + 255) / 256;      // 6250
    const int NB_SC = (NN + 1023) / 1024;    // 98
    const int NB_W  = (NN + 3) / 4;          // 25000 (4 waves/block)

    k_count<<<NB_E, 256, 0, stream>>>(erow, degp);
    k_scan1<<<NB_SC, 1024, 0, stream>>>(degp, rs, bsum);
    k_scan2<<<1, 128, 0, stream>>>(bsum, NB_SC);
    k_scan3<<<NB_SC, 1024, 0, stream>>>(degp, rs, bsum, normf);
    k_fill<<<NB_E, 256, 0, stream>>>(erow, ecol, rs, cursorp, csr);
    k_sortwave<<<NB_W, 256, 0, stream>>>(rs, csr);

    k_cbnorm<<<NL * NQ * KK, 128, 0, stream>>>(cbs, cbn);
    k_gemm<<<NN / 32, 256, 0, stream>>>(x, w_in, b_in, hbuf);

    for (int layer = 0; layer < NL; ++layer) {
        k_spmm<<<NN / 8, 256, 0, stream>>>(hbuf, normf, rs, csr, agg);
        k_fused<<<FUSED_BLOCKS, 512, 0, stream>>>(agg, hbuf, normf,
                                                  cbn + (size_t)layer * LAYER_CBN,
                                                  idsf, lpart, layer);
    }

    k_loss_reduce<<<1, 256, 0, stream>>>(lpart, loss);
}

// Round 12
// 919.962 us; speedup vs baseline: 1.0765x; 1.0087x over previous
//
#include <hip/hip_runtime.h>

#define NN 100000
#define EE 1600000
#define DD 128
#define NL 3
#define NQ 3
#define KK 16
#define ROWS_PER_FBLOCK 64
#define FUSED_BLOCKS ((NN + ROWS_PER_FBLOCK - 1) / ROWS_PER_FBLOCK)   // 1563
#define LPART_COUNT (NL * FUSED_BLOCKS)
#define EPT 8                         // edges per thread in count/fill
#define EPB (256 * EPT)               // edges per block = 2048

// permuted codebook layout (words): entry k, dim = sq*32 + i*4 + d  lives at
//   (layer*NQ + q)*QSTRIDE + i*ISTRIDE + k*16 + sq*4 + d
// so the dot-read for lane l (= kq*4+sq) is a linear float4 at i*ISTRIDE + l*4.
#define ISTRIDE 260                  // 64 lanes*4 words + 4 pad (bank shear)
#define QSTRIDE (8 * ISTRIDE)        // 2080 words per (layer,q)
#define LAYER_CBN (NQ * QSTRIDE)     // 6240 words per layer
// resid layout (words): dim = s*32 + j -> s*RSTRIDE + j
#define RSTRIDE 36
#define RBUF 144                     // keeps rows 16B aligned

// ---- workspace layout (bytes) ----
// The padded deg/cursor arrays (atomic line-contention fix: one row per 64B
// line) alias the AGG region — they are dead before the first k_spmm runs.
static constexpr size_t OFF_AGG   = 0;          // N*D f32       = 51,200,000
static constexpr size_t OFF_DEGP  = 0;          // N*16 i32      =  6,400,000 (aliases AGG)
static constexpr size_t OFF_CURP  = 6400000;    // N*16 i32      =  6,400,000 (aliases AGG)
static constexpr size_t OFF_CSR   = 51200000;   // E   i32       =  6,400,000
static constexpr size_t OFF_CBN   = 57600000;   // 9*2080 f32    =     74,880
static constexpr size_t OFF_NORM  = 57904128;   // N   f32       =    400,000
static constexpr size_t OFF_RS    = 59104128;   // (N+1) i32     =    400,004
static constexpr size_t OFF_BSUM  = 59504640;   // 128 i32
static constexpr size_t OFF_LPART = 59505152;   // NL*1563 f32
static constexpr size_t WS_NEEDED = 59805152;

// ---------- CSR build ----------
// 8 edges per thread: 8 independent atomic chains in flight per thread
// (vs 1 before) -> amortizes the device-scope atomic round-trip latency.
__global__ __launch_bounds__(256) void k_count(const int* __restrict__ erow,
                                               int* __restrict__ degp) {
    int base = blockIdx.x * EPB + threadIdx.x;
#pragma unroll
    for (int u = 0; u < EPT; ++u) {
        int e = base + u * 256;
        if (e < EE) atomicAdd(&degp[erow[e] << 4], 1);   // fire-and-forget
    }
}

__global__ __launch_bounds__(1024) void k_scan1(const int* __restrict__ degp,
                                                int* __restrict__ rs,
                                                int* __restrict__ bsum) {
    __shared__ int s[1024];
    int tid = threadIdx.x;
    int idx = blockIdx.x * 1024 + tid;
    int v = (idx < NN) ? degp[idx << 4] : 0;
    s[tid] = v;
    __syncthreads();
    for (int o = 1; o < 1024; o <<= 1) {
        int t2 = s[tid];
        if (tid >= o) t2 += s[tid - o];
        __syncthreads();
        s[tid] = t2;
        __syncthreads();
    }
    if (idx < NN) rs[idx] = s[tid] - v;       // exclusive
    if (tid == 1023) bsum[blockIdx.x] = s[1023];
}

__global__ __launch_bounds__(128) void k_scan2(int* __restrict__ bsum, int nb) {
    __shared__ int s[128];
    int tid = threadIdx.x;
    int v = (tid < nb) ? bsum[tid] : 0;
    s[tid] = v;
    __syncthreads();
    for (int o = 1; o < 128; o <<= 1) {
        int t2 = s[tid];
        if (tid >= o) t2 += s[tid - o];
        __syncthreads();
        s[tid] = t2;
        __syncthreads();
    }
    if (tid < nb) bsum[tid] = s[tid] - v;     // exclusive
}

__global__ __launch_bounds__(1024) void k_scan3(const int* __restrict__ degp,
                                                int* __restrict__ rs,
                                                const int* __restrict__ bsum,
                                                float* __restrict__ normf) {
    int idx = blockIdx.x * 1024 + threadIdx.x;
    if (idx < NN) {
        rs[idx] += bsum[blockIdx.x];
        normf[idx] = rsqrtf(1.0f + (float)degp[idx << 4]);
    }
    if (idx == 0) rs[NN] = EE;
}

// 8 independent atomic->store chains per thread, batch-phased so all 8
// atomics issue before any dependent store is needed.
__global__ __launch_bounds__(256) void k_fill(const int* __restrict__ erow,
                                              const int* __restrict__ ecol,
                                              const int* __restrict__ rs,
                                              int* __restrict__ cursorp,
                                              int* __restrict__ csr) {
    int base = blockIdx.x * EPB + threadIdx.x;
    int r[EPT], c[EPT], p[EPT];
#pragma unroll
    for (int u = 0; u < EPT; ++u) {
        int e = base + u * 256;
        r[u] = (e < EE) ? erow[e] : -1;
        c[u] = (e < EE) ? ecol[e] : 0;
    }
#pragma unroll
    for (int u = 0; u < EPT; ++u)
        if (r[u] >= 0) p[u] = atomicAdd(&cursorp[r[u] << 4], 1);
#pragma unroll
    for (int u = 0; u < EPT; ++u)
        if (r[u] >= 0) csr[rs[r[u]] + p[u]] = c[u];
}

// ---------- canonicalize neighbor order (determinism across replays) ----------
__global__ __launch_bounds__(256) void k_sortwave(const int* __restrict__ rs,
                                                  int* __restrict__ csr) {
    int wid = (blockIdx.x * 256 + threadIdx.x) >> 6;   // one wave per row
    int l = threadIdx.x & 63;
    if (wid >= NN) return;
    int s0 = rs[wid], e0 = rs[wid + 1];
    int deg = e0 - s0;
    if (deg <= 1) return;
    if (deg <= 64) {
        int v = (l < deg) ? csr[s0 + l] : 0x7fffffff;
        int rank = 0;
#pragma unroll 8
        for (int m = 0; m < 64; ++m) {
            int vm = __shfl(v, m);
            bool less = (vm < v) || (vm == v && m < l);
            rank += (m < deg && less) ? 1 : 0;
        }
        if (l < deg) csr[s0 + rank] = v;
    } else if (l == 0) {                    // vanishingly rare fallback
        for (int i = s0 + 1; i < e0; ++i) {
            int v = csr[i];
            int j = i - 1;
            while (j >= s0 && csr[j] > v) { csr[j + 1] = csr[j]; --j; }
            csr[j + 1] = v;
        }
    }
}

// ---------- codebook normalize -> permuted layout ----------
__global__ __launch_bounds__(128) void k_cbnorm(const float* __restrict__ cb,
                                                float* __restrict__ cbn) {
    __shared__ float s[128];
    int row = blockIdx.x;                 // (layer*NQ + q)*KK + k
    int tid = threadIdx.x;
    float v = cb[row * DD + tid];
    s[tid] = v * v;
    __syncthreads();
    for (int o = 64; o > 0; o >>= 1) {
        if (tid < o) s[tid] += s[tid + o];
        __syncthreads();
    }
    float inv = 1.0f / (sqrtf(s[0]) + 1e-12f);
    int lq = row >> 4;                    // layer*NQ + q  (0..8)
    int k  = row & 15;
    int sq = tid >> 5, ii = (tid >> 2) & 7, d = tid & 3;
    cbn[(size_t)lq * QSTRIDE + ii * ISTRIDE + k * 16 + sq * 4 + d] = v * inv;
}

// ---------- input linear: h = x @ w + b (LDS-staged w, 4x4 register tile) ----
__global__ __launch_bounds__(256) void k_gemm(const float* __restrict__ x,
                                              const float* __restrict__ w,
                                              const float* __restrict__ bias,
                                              float* __restrict__ h) {
    __shared__ float wls[64][DD];   // 32 KiB (one k-chunk of w)
    __shared__ float xs[32][DD];    // 16 KiB
    int tid = threadIdx.x;
    int rbase = blockIdx.x * 32;
    int cg = tid & 31;              // col group (4 cols)
    int rg = tid >> 5;              // row group (4 rows)

#pragma unroll
    for (int p = 0; p < 4; ++p) {   // stage x tile: 32x128
        int i = p * 256 + tid;
        int r = i >> 5, c = (i & 31) * 4;
        *(float4*)&xs[r][c] = *(const float4*)&x[(size_t)(rbase + r) * DD + c];
    }

    float4 acc[4];
#pragma unroll
    for (int i = 0; i < 4; ++i) acc[i] = make_float4(0.f, 0.f, 0.f, 0.f);

    for (int chunk = 0; chunk < 2; ++chunk) {
        __syncthreads();
#pragma unroll
        for (int p = 0; p < 8; ++p) {   // stage w chunk: 64x128
            int i = p * 256 + tid;
            int kr = i >> 5, c = (i & 31) * 4;
            *(float4*)&wls[kr][c] = *(const float4*)&w[(size_t)(chunk * 64 + kr) * DD + c];
        }
        __syncthreads();
#pragma unroll 4
        for (int kk = 0; kk < 64; ++kk) {
            float4 wv = *(const float4*)&wls[kk][cg * 4];
            int k = chunk * 64 + kk;
#pragma unroll
            for (int i = 0; i < 4; ++i) {
                float xv = xs[rg * 4 + i][k];
                acc[i].x += xv * wv.x; acc[i].y += xv * wv.y;
                acc[i].z += xv * wv.z; acc[i].w += xv * wv.w;
            }
        }
    }

    float4 bv = *(const float4*)&bias[cg * 4];
#pragma unroll
    for (int i = 0; i < 4; ++i) {
        float4 o;
        o.x = acc[i].x + bv.x; o.y = acc[i].y + bv.y;
        o.z = acc[i].z + bv.z; o.w = acc[i].w + bv.w;
        *(float4*)&h[(size_t)(rbase + rg * 4 + i) * DD + cg * 4] = o;
    }
}

// ---------- SpMM: agg[r] = sum_{c in neigh(r)} norm[c]*h[c] ----------
// 32 lanes per row (float4 each), 8 rows per 256-block, unroll-by-16 MLP.
// Per-component chains: ascending j, one fma per term -> bit-identical agg.
__global__ __launch_bounds__(256) void k_spmm(const float* __restrict__ h,
                                              const float* __restrict__ normf,
                                              const int* __restrict__ rs,
                                              const int* __restrict__ csr,
                                              float* __restrict__ agg) {
    int lane = threadIdx.x & 31;
    int slot = threadIdx.x >> 5;
    int r = blockIdx.x * 8 + slot;
    int s0 = rs[r], e0 = rs[r + 1];
    int off = lane << 2;

    float ax = 0.f, ay = 0.f, az = 0.f, aw = 0.f;
    int j = s0;
    for (; j + 16 <= e0; j += 16) {
        int c[16]; float n[16]; float4 v[16];
#pragma unroll
        for (int u = 0; u < 16; ++u) c[u] = csr[j + u];
#pragma unroll
        for (int u = 0; u < 16; ++u) n[u] = normf[c[u]];
#pragma unroll
        for (int u = 0; u < 16; ++u) v[u] = *(const float4*)&h[(size_t)c[u] * DD + off];
#pragma unroll
        for (int u = 0; u < 16; ++u) {
            ax += n[u] * v[u].x; ay += n[u] * v[u].y;
            az += n[u] * v[u].z; aw += n[u] * v[u].w;
        }
    }
    for (; j + 8 <= e0; j += 8) {
        int c[8]; float n[8]; float4 v[8];
#pragma unroll
        for (int u = 0; u < 8; ++u) c[u] = csr[j + u];
#pragma unroll
        for (int u = 0; u < 8; ++u) n[u] = normf[c[u]];
#pragma unroll
        for (int u = 0; u < 8; ++u) v[u] = *(const float4*)&h[(size_t)c[u] * DD + off];
#pragma unroll
        for (int u = 0; u < 8; ++u) {
            ax += n[u] * v[u].x; ay += n[u] * v[u].y;
            az += n[u] * v[u].z; aw += n[u] * v[u].w;
        }
    }
    for (; j + 4 <= e0; j += 4) {
        int c[4]; float n[4]; float4 v[4];
#pragma unroll
        for (int u = 0; u < 4; ++u) c[u] = csr[j + u];
#pragma unroll
        for (int u = 0; u < 4; ++u) n[u] = normf[c[u]];
#pragma unroll
        for (int u = 0; u < 4; ++u) v[u] = *(const float4*)&h[(size_t)c[u] * DD + off];
#pragma unroll
        for (int u = 0; u < 4; ++u) {
            ax += n[u] * v[u].x; ay += n[u] * v[u].y;
            az += n[u] * v[u].z; aw += n[u] * v[u].w;
        }
    }
    for (; j < e0; ++j) {
        int c = csr[j];
        float ns = normf[c];
        float4 v = *(const float4*)&h[(size_t)c * DD + off];
        ax += ns * v.x;
        ay += ns * v.y;
        az += ns * v.z;
        aw += ns * v.w;
    }
    float4 o = {ax, ay, az, aw};
    *(float4*)&agg[(size_t)r * DD + off] = o;
}

// ---------- fused: x1 = norm*(agg + norm*h); residual VQ; h += x1 ----------
// 512 threads = 8 waves/block; resid exchange wave-private + barrier-free
// (validated R9-R11).
__global__ __launch_bounds__(512) void k_fused(const float* __restrict__ agg,
                                               float* __restrict__ h,
                                               const float* __restrict__ normf,
                                               const float* __restrict__ cbn_layer,
                                               float* __restrict__ idsf,
                                               float* __restrict__ lpart,
                                               int layer) {
    __shared__ float cb_s[LAYER_CBN];        // 24,960 B (permuted layout)
    __shared__ float resid_s[8][RBUF];       // padded resid (stride 36/slice)
    __shared__ float wsum[8];
    int tid = threadIdx.x;

    {   // linear copy: global cbn is already in the permuted layout
        const float4* src = (const float4*)cbn_layer;
        float4* dst = (float4*)cb_s;
        for (int t = tid; t < LAYER_CBN / 4; t += 512) dst[t] = src[t];
    }
    __syncthreads();

    int w = tid >> 6;      // wave id (0..7)
    int l = tid & 63;      // lane
    int rwrd = (l >> 4) * RSTRIDE + ((2 * l) & 31);           // resid write word
    int sq = l & 3;                                            // resid read slice
    int cb2 = ((l >> 1) & 7) * ISTRIDE + (l >> 4) * 4 + 2 * (l & 1); // cb[?][2l] word
    float lsum = 0.f;

    for (int it = 0; it < ROWS_PER_FBLOCK / 8; ++it) {
        int r = blockIdx.x * ROWS_PER_FBLOCK + it * 8 + w;
        if (r < NN) {                        // wave-uniform guard (tail block)
            float nr = normf[r];
            float2 hv = *(const float2*)&h[(size_t)r * DD + 2 * l];
            float2 av = *(const float2*)&agg[(size_t)r * DD + 2 * l];
            float x0 = nr * (av.x + nr * hv.x);
            float x1 = nr * (av.y + nr * hv.y);
            float r0 = x0, r1 = x1;

            for (int q = 0; q < NQ; ++q) {
                *(float2*)&resid_s[w][rwrd] = make_float2(r0, r1);
                // wave-synchronous: same-wave ds_write -> ds_read

                const float* cbq = &cb_s[q * QSTRIDE];
                const float* rsd = resid_s[w];
                float pd = 0.f;
#pragma unroll
                for (int i = 0; i < 8; ++i) {
                    float4 cv = *(const float4*)&cbq[i * ISTRIDE + l * 4];
                    float4 rv = *(const float4*)&rsd[sq * RSTRIDE + i * 4];
                    pd += cv.x * rv.x + cv.y * rv.y + cv.z * rv.z + cv.w * rv.w;
                }
                pd += __shfl_xor(pd, 1);
                pd += __shfl_xor(pd, 2);   // full dot(resid, cbn[kq]) in each quad

                float best = pd;
                int bk = l >> 2;
                for (int m = 4; m < 64; m <<= 1) {
                    float ov = __shfl_xor(best, m);
                    int oi = __shfl_xor(bk, m);
                    if (ov > best || (ov == best && oi < bk)) { best = ov; bk = oi; }
                }
                // bk = argmax (min index on tie), agreed by all lanes

                float2 cv2 = *(const float2*)&cb_s[q * QSTRIDE + bk * 16 + cb2];
                r0 -= cv2.x;
                r1 -= cv2.y;
                lsum += r0 * r0 + r1 * r1;

                if (l == 0) idsf[(size_t)r * (NL * NQ) + layer * NQ + q] = (float)bk;
            }

            *(float2*)&h[(size_t)r * DD + 2 * l] = make_float2(x0 + hv.x, x1 + hv.y);
        }
    }

    // block loss partial (deterministic)
#pragma unroll
    for (int m = 1; m < 64; m <<= 1) lsum += __shfl_xor(lsum, m);
    if (l == 0) wsum[w] = lsum;
    __syncthreads();
    if (tid == 0) {
        float tot = 0.f;
#pragma unroll
        for (int i = 0; i < 8; ++i) tot += wsum[i];
        lpart[layer * FUSED_BLOCKS + blockIdx.x] = tot * (0.25f / (float)(NN * DD));
    }
}

__global__ __launch_bounds__(256) void k_loss_reduce(const float* __restrict__ part,
                                                     float* __restrict__ out_loss) {
    __shared__ float s[256];
    float a = 0.f;
    for (int i = threadIdx.x; i < LPART_COUNT; i += 256) a += part[i];
    s[threadIdx.x] = a;
    __syncthreads();
    for (int o = 128; o > 0; o >>= 1) {
        if (threadIdx.x < o) s[threadIdx.x] += s[threadIdx.x + o];
        __syncthreads();
    }
    if (threadIdx.x == 0) out_loss[0] = s[0];
}

extern "C" void kernel_launch(void* const* d_in, const int* in_sizes, int n_in,
                              void* d_out, int out_size, void* d_ws, size_t ws_size,
                              hipStream_t stream) {
    if (ws_size < WS_NEEDED) return;

    const float* x    = (const float*)d_in[0];
    const float* w_in = (const float*)d_in[1];
    const float* b_in = (const float*)d_in[2];
    const float* cbs  = (const float*)d_in[3];
    const int*   erow = (const int*)d_in[4];
    const int*   ecol = (const int*)d_in[5];

    float* out  = (float*)d_out;
    float* hbuf = out;                                   // [N][D] working h = output 0
    float* loss = out + (size_t)NN * DD;                 // scalar output 1
    float* idsf = out + (size_t)NN * DD + 1;             // [N][9] output 2 (as float)

    char* ws = (char*)d_ws;
    float* agg     = (float*)(ws + OFF_AGG);
    int*   degp    = (int*)(ws + OFF_DEGP);              // aliases agg (dead before spmm)
    int*   cursorp = (int*)(ws + OFF_CURP);              // aliases agg (dead before spmm)
    int*   csr     = (int*)(ws + OFF_CSR);
    float* cbn     = (float*)(ws + OFF_CBN);
    float* normf   = (float*)(ws + OFF_NORM);
    int*   rs      = (int*)(ws + OFF_RS);
    int*   bsum    = (int*)(ws + OFF_BSUM);
    float* lpart   = (float*)(ws + OFF_LPART);

    // zero padded deg + cursor (12.8 MB, contiguous at front of agg region)
    hipMemsetAsync(ws + OFF_DEGP, 0, 12800000, stream);

    const int NB_B  = (EE + EPB - 1) / EPB;  // 782 (batched count/fill)
    const int NB_SC = (NN + 1023) / 1024;    // 98
    const int NB_W  = (NN + 3) / 4;          // 25000 (4 waves/block)

    k_count<<<NB_B, 256, 0, stream>>>(erow, degp);
    k_scan1<<<NB_SC, 1024, 0, stream>>>(degp, rs, bsum);
    k_scan2<<<1, 128, 0, stream>>>(bsum, NB_SC);
    k_scan3<<<NB_SC, 1024, 0, stream>>>(degp, rs, bsum, normf);
    k_fill<<<NB_B, 256, 0, stream>>>(erow, ecol, rs, cursorp, csr);
    k_sortwave<<<NB_W, 256, 0, stream>>>(rs, csr);

    k_cbnorm<<<NL * NQ * KK, 128, 0, stream>>>(cbs, cbn);
    k_gemm<<<NN / 32, 256, 0, stream>>>(x, w_in, b_in, hbuf);

    for (int layer = 0; layer < NL; ++layer) {
        k_spmm<<<NN / 8, 256, 0, stream>>>(hbuf, normf, rs, csr, agg);
        k_fused<<<FUSED_BLOCKS, 512, 0, stream>>>(agg, hbuf, normf,
                                                  cbn + (size_t)layer * LAYER_CBN,
                                                  idsf, lpart, layer);
    }

    k_loss_reduce<<<1, 256, 0, stream>>>(lpart, loss);
}

// Round 13
// 852.178 us; speedup vs baseline: 1.1621x; 1.0795x over previous
//
#include <hip/hip_runtime.h>

#define NN 100000
#define EE 1600000
#define DD 128
#define NL 3
#define NQ 3
#define KK 16
#define ROWS_PER_FBLOCK 64
#define FUSED_BLOCKS ((NN + ROWS_PER_FBLOCK - 1) / ROWS_PER_FBLOCK)   // 1563
#define LPART_COUNT (NL * FUSED_BLOCKS)
#define EPT 8                         // edges per thread in fill
#define EPB (256 * EPT)               // edges per block = 2048
#define MAXDEG 64                     // fixed slots/row (P(deg>64) ~ 1e-13)

// permuted codebook layout (words): entry k, dim = sq*32 + i*4 + d  lives at
//   (layer*NQ + q)*QSTRIDE + i*ISTRIDE + k*16 + sq*4 + d
// so the dot-read for lane l (= kq*4+sq) is a linear float4 at i*ISTRIDE + l*4.
#define ISTRIDE 260                  // 64 lanes*4 words + 4 pad (bank shear)
#define QSTRIDE (8 * ISTRIDE)        // 2080 words per (layer,q)
#define LAYER_CBN (NQ * QSTRIDE)     // 6240 words per layer
// resid layout (words): dim = s*32 + j -> s*RSTRIDE + j
#define RSTRIDE 36
#define RBUF 144                     // keeps rows 16B aligned

// ---- workspace layout (bytes) ----
// csr_fixed (N*64 i32 = 25.6MB) and cursorp (N*16 i32 padded = 6.4MB) alias
// the AGG region — both are dead before the first k_spmm writes agg.
static constexpr size_t OFF_AGG   = 0;          // N*D f32       = 51,200,000
static constexpr size_t OFF_CSRF  = 0;          // N*64 i32      = 25,600,000 (aliases AGG)
static constexpr size_t OFF_CURP  = 25600000;   // N*16 i32      =  6,400,000 (aliases AGG)
static constexpr size_t OFF_CSR   = 51200000;   // E   i32       =  6,400,000
static constexpr size_t OFF_CBN   = 57600000;   // 9*2080 f32    =     74,880
static constexpr size_t OFF_NORM  = 57904128;   // N   f32       =    400,000
static constexpr size_t OFF_RS    = 59104128;   // (N+1) i32     =    400,004
static constexpr size_t OFF_BSUM  = 59504640;   // 128 i32
static constexpr size_t OFF_LPART = 59505152;   // NL*1563 f32
static constexpr size_t WS_NEEDED = 59805152;

// ---------- CSR build (no separate count kernel) ----------
// The fill's atomicAdd return value IS the slot; the final cursor value IS deg.
// 8 independent atomic->store chains per thread amortize atomic latency.
__global__ __launch_bounds__(256) void k_fill_fixed(const int* __restrict__ erow,
                                                    const int* __restrict__ ecol,
                                                    int* __restrict__ cursorp,
                                                    int* __restrict__ csrf) {
    int base = blockIdx.x * EPB + threadIdx.x;
    int r[EPT], c[EPT], p[EPT];
#pragma unroll
    for (int u = 0; u < EPT; ++u) {
        int e = base + u * 256;
        r[u] = (e < EE) ? erow[e] : -1;
        c[u] = (e < EE) ? ecol[e] : 0;
    }
#pragma unroll
    for (int u = 0; u < EPT; ++u)
        if (r[u] >= 0) p[u] = atomicAdd(&cursorp[r[u] << 4], 1);
#pragma unroll
    for (int u = 0; u < EPT; ++u)
        if (r[u] >= 0 && p[u] < MAXDEG) csrf[r[u] * MAXDEG + p[u]] = c[u];
}

__global__ __launch_bounds__(1024) void k_scan1(const int* __restrict__ cursorp,
                                                int* __restrict__ rs,
                                                int* __restrict__ bsum) {
    __shared__ int s[1024];
    int tid = threadIdx.x;
    int idx = blockIdx.x * 1024 + tid;
    int v = (idx < NN) ? cursorp[idx << 4] : 0;
    s[tid] = v;
    __syncthreads();
    for (int o = 1; o < 1024; o <<= 1) {
        int t2 = s[tid];
        if (tid >= o) t2 += s[tid - o];
        __syncthreads();
        s[tid] = t2;
        __syncthreads();
    }
    if (idx < NN) rs[idx] = s[tid] - v;       // exclusive
    if (tid == 1023) bsum[blockIdx.x] = s[1023];
}

__global__ __launch_bounds__(128) void k_scan2(int* __restrict__ bsum, int nb) {
    __shared__ int s[128];
    int tid = threadIdx.x;
    int v = (tid < nb) ? bsum[tid] : 0;
    s[tid] = v;
    __syncthreads();
    for (int o = 1; o < 128; o <<= 1) {
        int t2 = s[tid];
        if (tid >= o) t2 += s[tid - o];
        __syncthreads();
        s[tid] = t2;
        __syncthreads();
    }
    if (tid < nb) bsum[tid] = s[tid] - v;     // exclusive
}

__global__ __launch_bounds__(1024) void k_scan3(const int* __restrict__ cursorp,
                                                int* __restrict__ rs,
                                                const int* __restrict__ bsum,
                                                float* __restrict__ normf) {
    int idx = blockIdx.x * 1024 + threadIdx.x;
    if (idx < NN) {
        rs[idx] += bsum[blockIdx.x];
        normf[idx] = rsqrtf(1.0f + (float)cursorp[idx << 4]);
    }
    if (idx == 0) rs[NN] = EE;
}

// ---------- sort fixed slots -> compact canonical csr ----------
// Rank-sort ascending by col (ties: identical values -> order irrelevant for
// the FP sum). Output csr is bit-identical to the previous in-place sort.
__global__ __launch_bounds__(256) void k_sortcompact(const int* __restrict__ cursorp,
                                                     const int* __restrict__ rs,
                                                     const int* __restrict__ csrf,
                                                     int* __restrict__ csr) {
    int wid = (blockIdx.x * 256 + threadIdx.x) >> 6;   // one wave per row
    int l = threadIdx.x & 63;
    if (wid >= NN) return;
    int deg = cursorp[wid << 4];
    if (deg > MAXDEG) deg = MAXDEG;
    if (deg <= 0) return;
    int v = (l < deg) ? csrf[wid * MAXDEG + l] : 0x7fffffff;
    int rank = 0;
#pragma unroll 8
    for (int m = 0; m < 64; ++m) {
        int vm = __shfl(v, m);
        bool less = (vm < v) || (vm == v && m < l);
        rank += (m < deg && less) ? 1 : 0;
    }
    if (l < deg) csr[rs[wid] + rank] = v;
}

// ---------- codebook normalize -> permuted layout ----------
__global__ __launch_bounds__(128) void k_cbnorm(const float* __restrict__ cb,
                                                float* __restrict__ cbn) {
    __shared__ float s[128];
    int row = blockIdx.x;                 // (layer*NQ + q)*KK + k
    int tid = threadIdx.x;
    float v = cb[row * DD + tid];
    s[tid] = v * v;
    __syncthreads();
    for (int o = 64; o > 0; o >>= 1) {
        if (tid < o) s[tid] += s[tid + o];
        __syncthreads();
    }
    float inv = 1.0f / (sqrtf(s[0]) + 1e-12f);
    int lq = row >> 4;                    // layer*NQ + q  (0..8)
    int k  = row & 15;
    int sq = tid >> 5, ii = (tid >> 2) & 7, d = tid & 3;
    cbn[(size_t)lq * QSTRIDE + ii * ISTRIDE + k * 16 + sq * 4 + d] = v * inv;
}

// ---------- input linear: h = x @ w + b (LDS-staged w, 4x4 register tile) ----
__global__ __launch_bounds__(256) void k_gemm(const float* __restrict__ x,
                                              const float* __restrict__ w,
                                              const float* __restrict__ bias,
                                              float* __restrict__ h) {
    __shared__ float wls[64][DD];   // 32 KiB (one k-chunk of w)
    __shared__ float xs[32][DD];    // 16 KiB
    int tid = threadIdx.x;
    int rbase = blockIdx.x * 32;
    int cg = tid & 31;              // col group (4 cols)
    int rg = tid >> 5;              // row group (4 rows)

#pragma unroll
    for (int p = 0; p < 4; ++p) {   // stage x tile: 32x128
        int i = p * 256 + tid;
        int r = i >> 5, c = (i & 31) * 4;
        *(float4*)&xs[r][c] = *(const float4*)&x[(size_t)(rbase + r) * DD + c];
    }

    float4 acc[4];
#pragma unroll
    for (int i = 0; i < 4; ++i) acc[i] = make_float4(0.f, 0.f, 0.f, 0.f);

    for (int chunk = 0; chunk < 2; ++chunk) {
        __syncthreads();
#pragma unroll
        for (int p = 0; p < 8; ++p) {   // stage w chunk: 64x128
            int i = p * 256 + tid;
            int kr = i >> 5, c = (i & 31) * 4;
            *(float4*)&wls[kr][c] = *(const float4*)&w[(size_t)(chunk * 64 + kr) * DD + c];
        }
        __syncthreads();
#pragma unroll 4
        for (int kk = 0; kk < 64; ++kk) {
            float4 wv = *(const float4*)&wls[kk][cg * 4];
            int k = chunk * 64 + kk;
#pragma unroll
            for (int i = 0; i < 4; ++i) {
                float xv = xs[rg * 4 + i][k];
                acc[i].x += xv * wv.x; acc[i].y += xv * wv.y;
                acc[i].z += xv * wv.z; acc[i].w += xv * wv.w;
            }
        }
    }

    float4 bv = *(const float4*)&bias[cg * 4];
#pragma unroll
    for (int i = 0; i < 4; ++i) {
        float4 o;
        o.x = acc[i].x + bv.x; o.y = acc[i].y + bv.y;
        o.z = acc[i].z + bv.z; o.w = acc[i].w + bv.w;
        *(float4*)&h[(size_t)(rbase + rg * 4 + i) * DD + cg * 4] = o;
    }
}

// ---------- SpMM: agg[r] = sum_{c in neigh(r)} norm[c]*h[c] ----------
__global__ __launch_bounds__(256) void k_spmm(const float* __restrict__ h,
                                              const float* __restrict__ normf,
                                              const int* __restrict__ rs,
                                              const int* __restrict__ csr,
                                              float* __restrict__ agg) {
    int lane = threadIdx.x & 31;
    int slot = threadIdx.x >> 5;
    int r = blockIdx.x * 8 + slot;
    int s0 = rs[r], e0 = rs[r + 1];
    int off = lane << 2;

    float ax = 0.f, ay = 0.f, az = 0.f, aw = 0.f;
    int j = s0;
    for (; j + 16 <= e0; j += 16) {
        int c[16]; float n[16]; float4 v[16];
#pragma unroll
        for (int u = 0; u < 16; ++u) c[u] = csr[j + u];
#pragma unroll
        for (int u = 0; u < 16; ++u) n[u] = normf[c[u]];
#pragma unroll
        for (int u = 0; u < 16; ++u) v[u] = *(const float4*)&h[(size_t)c[u] * DD + off];
#pragma unroll
        for (int u = 0; u < 16; ++u) {
            ax += n[u] * v[u].x; ay += n[u] * v[u].y;
            az += n[u] * v[u].z; aw += n[u] * v[u].w;
        }
    }
    for (; j + 8 <= e0; j += 8) {
        int c[8]; float n[8]; float4 v[8];
#pragma unroll
        for (int u = 0; u < 8; ++u) c[u] = csr[j + u];
#pragma unroll
        for (int u = 0; u < 8; ++u) n[u] = normf[c[u]];
#pragma unroll
        for (int u = 0; u < 8; ++u) v[u] = *(const float4*)&h[(size_t)c[u] * DD + off];
#pragma unroll
        for (int u = 0; u < 8; ++u) {
            ax += n[u] * v[u].x; ay += n[u] * v[u].y;
            az += n[u] * v[u].z; aw += n[u] * v[u].w;
        }
    }
    for (; j + 4 <= e0; j += 4) {
        int c[4]; float n[4]; float4 v[4];
#pragma unroll
        for (int u = 0; u < 4; ++u) c[u] = csr[j + u];
#pragma unroll
        for (int u = 0; u < 4; ++u) n[u] = normf[c[u]];
#pragma unroll
        for (int u = 0; u < 4; ++u) v[u] = *(const float4*)&h[(size_t)c[u] * DD + off];
#pragma unroll
        for (int u = 0; u < 4; ++u) {
            ax += n[u] * v[u].x; ay += n[u] * v[u].y;
            az += n[u] * v[u].z; aw += n[u] * v[u].w;
        }
    }
    for (; j < e0; ++j) {
        int c = csr[j];
        float ns = normf[c];
        float4 v = *(const float4*)&h[(size_t)c * DD + off];
        ax += ns * v.x;
        ay += ns * v.y;
        az += ns * v.z;
        aw += ns * v.w;
    }
    float4 o = {ax, ay, az, aw};
    *(float4*)&agg[(size_t)r * DD + off] = o;
}

// ---------- fused: x1 = norm*(agg + norm*h); residual VQ; h += x1 ----------
// 512 threads = 8 waves/block; resid exchange wave-private + barrier-free
// (validated R9-R12).
__global__ __launch_bounds__(512) void k_fused(const float* __restrict__ agg,
                                               float* __restrict__ h,
                                               const float* __restrict__ normf,
                                               const float* __restrict__ cbn_layer,
                                               float* __restrict__ idsf,
                                               float* __restrict__ lpart,
                                               int layer) {
    __shared__ float cb_s[LAYER_CBN];        // 24,960 B (permuted layout)
    __shared__ float resid_s[8][RBUF];       // padded resid (stride 36/slice)
    __shared__ float wsum[8];
    int tid = threadIdx.x;

    {   // linear copy: global cbn is already in the permuted layout
        const float4* src = (const float4*)cbn_layer;
        float4* dst = (float4*)cb_s;
        for (int t = tid; t < LAYER_CBN / 4; t += 512) dst[t] = src[t];
    }
    __syncthreads();

    int w = tid >> 6;      // wave id (0..7)
    int l = tid & 63;      // lane
    int rwrd = (l >> 4) * RSTRIDE + ((2 * l) & 31);           // resid write word
    int sq = l & 3;                                            // resid read slice
    int cb2 = ((l >> 1) & 7) * ISTRIDE + (l >> 4) * 4 + 2 * (l & 1); // cb[?][2l] word
    float lsum = 0.f;

    for (int it = 0; it < ROWS_PER_FBLOCK / 8; ++it) {
        int r = blockIdx.x * ROWS_PER_FBLOCK + it * 8 + w;
        if (r < NN) {                        // wave-uniform guard (tail block)
            float nr = normf[r];
            float2 hv = *(const float2*)&h[(size_t)r * DD + 2 * l];
            float2 av = *(const float2*)&agg[(size_t)r * DD + 2 * l];
            float x0 = nr * (av.x + nr * hv.x);
            float x1 = nr * (av.y + nr * hv.y);
            float r0 = x0, r1 = x1;

            for (int q = 0; q < NQ; ++q) {
                *(float2*)&resid_s[w][rwrd] = make_float2(r0, r1);
                // wave-synchronous: same-wave ds_write -> ds_read

                const float* cbq = &cb_s[q * QSTRIDE];
                const float* rsd = resid_s[w];
                float pd = 0.f;
#pragma unroll
                for (int i = 0; i < 8; ++i) {
                    float4 cv = *(const float4*)&cbq[i * ISTRIDE + l * 4];
                    float4 rv = *(const float4*)&rsd[sq * RSTRIDE + i * 4];
                    pd += cv.x * rv.x + cv.y * rv.y + cv.z * rv.z + cv.w * rv.w;
                }
                pd += __shfl_xor(pd, 1);
                pd += __shfl_xor(pd, 2);   // full dot(resid, cbn[kq]) in each quad

                float best = pd;
                int bk = l >> 2;
                for (int m = 4; m < 64; m <<= 1) {
                    float ov = __shfl_xor(best, m);
                    int oi = __shfl_xor(bk, m);
                    if (ov > best || (ov == best && oi < bk)) { best = ov; bk = oi; }
                }
                // bk = argmax (min index on tie), agreed by all lanes

                float2 cv2 = *(const float2*)&cb_s[q * QSTRIDE + bk * 16 + cb2];
                r0 -= cv2.x;
                r1 -= cv2.y;
                lsum += r0 * r0 + r1 * r1;

                if (l == 0) idsf[(size_t)r * (NL * NQ) + layer * NQ + q] = (float)bk;
            }

            *(float2*)&h[(size_t)r * DD + 2 * l] = make_float2(x0 + hv.x, x1 + hv.y);
        }
    }

    // block loss partial (deterministic)
#pragma unroll
    for (int m = 1; m < 64; m <<= 1) lsum += __shfl_xor(lsum, m);
    if (l == 0) wsum[w] = lsum;
    __syncthreads();
    if (tid == 0) {
        float tot = 0.f;
#pragma unroll
        for (int i = 0; i < 8; ++i) tot += wsum[i];
        lpart[layer * FUSED_BLOCKS + blockIdx.x] = tot * (0.25f / (float)(NN * DD));
    }
}

__global__ __launch_bounds__(256) void k_loss_reduce(const float* __restrict__ part,
                                                     float* __restrict__ out_loss) {
    __shared__ float s[256];
    float a = 0.f;
    for (int i = threadIdx.x; i < LPART_COUNT; i += 256) a += part[i];
    s[threadIdx.x] = a;
    __syncthreads();
    for (int o = 128; o > 0; o >>= 1) {
        if (threadIdx.x < o) s[threadIdx.x] += s[threadIdx.x + o];
        __syncthreads();
    }
    if (threadIdx.x == 0) out_loss[0] = s[0];
}

extern "C" void kernel_launch(void* const* d_in, const int* in_sizes, int n_in,
                              void* d_out, int out_size, void* d_ws, size_t ws_size,
                              hipStream_t stream) {
    if (ws_size < WS_NEEDED) return;

    const float* x    = (const float*)d_in[0];
    const float* w_in = (const float*)d_in[1];
    const float* b_in = (const float*)d_in[2];
    const float* cbs  = (const float*)d_in[3];
    const int*   erow = (const int*)d_in[4];
    const int*   ecol = (const int*)d_in[5];

    float* out  = (float*)d_out;
    float* hbuf = out;                                   // [N][D] working h = output 0
    float* loss = out + (size_t)NN * DD;                 // scalar output 1
    float* idsf = out + (size_t)NN * DD + 1;             // [N][9] output 2 (as float)

    char* ws = (char*)d_ws;
    float* agg     = (float*)(ws + OFF_AGG);
    int*   csrf    = (int*)(ws + OFF_CSRF);              // aliases agg (dead before spmm)
    int*   cursorp = (int*)(ws + OFF_CURP);              // aliases agg (dead before spmm)
    int*   csr     = (int*)(ws + OFF_CSR);
    float* cbn     = (float*)(ws + OFF_CBN);
    float* normf   = (float*)(ws + OFF_NORM);
    int*   rs      = (int*)(ws + OFF_RS);
    int*   bsum    = (int*)(ws + OFF_BSUM);
    float* lpart   = (float*)(ws + OFF_LPART);

    // zero padded cursor (6.4 MB)
    hipMemsetAsync(ws + OFF_CURP, 0, 6400000, stream);

    const int NB_B  = (EE + EPB - 1) / EPB;  // 782 (batched fill)
    const int NB_SC = (NN + 1023) / 1024;    // 98
    const int NB_W  = (NN + 3) / 4;          // 25000 (4 waves/block)

    k_fill_fixed<<<NB_B, 256, 0, stream>>>(erow, ecol, cursorp, csrf);
    k_scan1<<<NB_SC, 1024, 0, stream>>>(cursorp, rs, bsum);
    k_scan2<<<1, 128, 0, stream>>>(bsum, NB_SC);
    k_scan3<<<NB_SC, 1024, 0, stream>>>(cursorp, rs, bsum, normf);
    k_sortcompact<<<NB_W, 256, 0, stream>>>(cursorp, rs, csrf, csr);

    k_cbnorm<<<NL * NQ * KK, 128, 0, stream>>>(cbs, cbn);
    k_gemm<<<NN / 32, 256, 0, stream>>>(x, w_in, b_in, hbuf);

    for (int layer = 0; layer < NL; ++layer) {
        k_spmm<<<NN / 8, 256, 0, stream>>>(hbuf, normf, rs, csr, agg);
        k_fused<<<FUSED_BLOCKS, 512, 0, stream>>>(agg, hbuf, normf,
                                                  cbn + (size_t)layer * LAYER_CBN,
                                                  idsf, lpart, layer);
    }

    k_loss_reduce<<<1, 256, 0, stream>>>(lpart, loss);
}

// Round 14
// 814.586 us; speedup vs baseline: 1.2157x; 1.0461x over previous
//
#include <hip/hip_runtime.h>

#define NN 100000
#define EE 1600000
#define DD 128
#define NL 3
#define NQ 3
#define KK 16
#define ROWS_PER_FBLOCK 64
#define FUSED_BLOCKS ((NN + ROWS_PER_FBLOCK - 1) / ROWS_PER_FBLOCK)   // 1563
#define LPART_COUNT (NL * FUSED_BLOCKS)
#define EPT 8                         // edges per thread in fill
#define EPB (256 * EPT)               // edges per block = 2048
#define MAXDEG 64                     // fixed slots/row (P(deg>64) ~ 1e-13)

// permuted codebook layout (words): entry k, dim = sq*32 + i*4 + d  lives at
//   (layer*NQ + q)*QSTRIDE + i*ISTRIDE + k*16 + sq*4 + d
#define ISTRIDE 260
#define QSTRIDE (8 * ISTRIDE)        // 2080 words per (layer,q)
#define LAYER_CBN (NQ * QSTRIDE)     // 6240 words per layer
#define RSTRIDE 36
#define RBUF 144

// ---- workspace layout (bytes) ----
// ha is the ping-pong h buffer; csrf/cursorp alias it (dead before k_gemm
// writes ha — the CSR chain completes first in stream order).
static constexpr size_t OFF_HA    = 0;          // N*D f32       = 51,200,000
static constexpr size_t OFF_CSRF  = 0;          // N*64 i32      = 25,600,000 (aliases HA)
static constexpr size_t OFF_CURP  = 25600000;   // N*16 i32      =  6,400,000 (aliases HA)
static constexpr size_t OFF_CSR   = 51200000;   // E   i32       =  6,400,000
static constexpr size_t OFF_CBN   = 57600000;   // 9*2080 f32    =     74,880
static constexpr size_t OFF_NORM  = 57904128;   // N   f32       =    400,000
static constexpr size_t OFF_RS    = 59104128;   // (N+1) i32     =    400,004
static constexpr size_t OFF_BSUM  = 59504640;   // 128 i32
static constexpr size_t OFF_LPART = 59505152;   // NL*1563 f32
static constexpr size_t WS_NEEDED = 59805152;

// ---------- CSR build (no separate count kernel) ----------
__global__ __launch_bounds__(256) void k_fill_fixed(const int* __restrict__ erow,
                                                    const int* __restrict__ ecol,
                                                    int* __restrict__ cursorp,
                                                    int* __restrict__ csrf) {
    int base = blockIdx.x * EPB + threadIdx.x;
    int r[EPT], c[EPT], p[EPT];
#pragma unroll
    for (int u = 0; u < EPT; ++u) {
        int e = base + u * 256;
        r[u] = (e < EE) ? erow[e] : -1;
        c[u] = (e < EE) ? ecol[e] : 0;
    }
#pragma unroll
    for (int u = 0; u < EPT; ++u)
        if (r[u] >= 0) p[u] = atomicAdd(&cursorp[r[u] << 4], 1);
#pragma unroll
    for (int u = 0; u < EPT; ++u)
        if (r[u] >= 0 && p[u] < MAXDEG) csrf[r[u] * MAXDEG + p[u]] = c[u];
}

__global__ __launch_bounds__(1024) void k_scan1(const int* __restrict__ cursorp,
                                                int* __restrict__ rs,
                                                int* __restrict__ bsum) {
    __shared__ int s[1024];
    int tid = threadIdx.x;
    int idx = blockIdx.x * 1024 + tid;
    int v = (idx < NN) ? cursorp[idx << 4] : 0;
    s[tid] = v;
    __syncthreads();
    for (int o = 1; o < 1024; o <<= 1) {
        int t2 = s[tid];
        if (tid >= o) t2 += s[tid - o];
        __syncthreads();
        s[tid] = t2;
        __syncthreads();
    }
    if (idx < NN) rs[idx] = s[tid] - v;       // exclusive
    if (tid == 1023) bsum[blockIdx.x] = s[1023];
}

__global__ __launch_bounds__(128) void k_scan2(int* __restrict__ bsum, int nb) {
    __shared__ int s[128];
    int tid = threadIdx.x;
    int v = (tid < nb) ? bsum[tid] : 0;
    s[tid] = v;
    __syncthreads();
    for (int o = 1; o < 128; o <<= 1) {
        int t2 = s[tid];
        if (tid >= o) t2 += s[tid - o];
        __syncthreads();
        s[tid] = t2;
        __syncthreads();
    }
    if (tid < nb) bsum[tid] = s[tid] - v;     // exclusive
}

__global__ __launch_bounds__(1024) void k_scan3(const int* __restrict__ cursorp,
                                                int* __restrict__ rs,
                                                const int* __restrict__ bsum,
                                                float* __restrict__ normf) {
    int idx = blockIdx.x * 1024 + threadIdx.x;
    if (idx < NN) {
        rs[idx] += bsum[blockIdx.x];
        normf[idx] = rsqrtf(1.0f + (float)cursorp[idx << 4]);
    }
    if (idx == 0) rs[NN] = EE;
}

// ---------- sort fixed slots -> compact canonical csr ----------
__global__ __launch_bounds__(256) void k_sortcompact(const int* __restrict__ cursorp,
                                                     const int* __restrict__ rs,
                                                     const int* __restrict__ csrf,
                                                     int* __restrict__ csr) {
    int wid = (blockIdx.x * 256 + threadIdx.x) >> 6;   // one wave per row
    int l = threadIdx.x & 63;
    if (wid >= NN) return;
    int deg = cursorp[wid << 4];
    if (deg > MAXDEG) deg = MAXDEG;
    if (deg <= 0) return;
    int v = (l < deg) ? csrf[wid * MAXDEG + l] : 0x7fffffff;
    int rank = 0;
#pragma unroll 8
    for (int m = 0; m < 64; ++m) {
        int vm = __shfl(v, m);
        bool less = (vm < v) || (vm == v && m < l);
        rank += (m < deg && less) ? 1 : 0;
    }
    if (l < deg) csr[rs[wid] + rank] = v;
}

// ---------- codebook normalize -> permuted layout ----------
__global__ __launch_bounds__(128) void k_cbnorm(const float* __restrict__ cb,
                                                float* __restrict__ cbn) {
    __shared__ float s[128];
    int row = blockIdx.x;                 // (layer*NQ + q)*KK + k
    int tid = threadIdx.x;
    float v = cb[row * DD + tid];
    s[tid] = v * v;
    __syncthreads();
    for (int o = 64; o > 0; o >>= 1) {
        if (tid < o) s[tid] += s[tid + o];
        __syncthreads();
    }
    float inv = 1.0f / (sqrtf(s[0]) + 1e-12f);
    int lq = row >> 4;                    // layer*NQ + q  (0..8)
    int k  = row & 15;
    int sq = tid >> 5, ii = (tid >> 2) & 7, d = tid & 3;
    cbn[(size_t)lq * QSTRIDE + ii * ISTRIDE + k * 16 + sq * 4 + d] = v * inv;
}

// ---------- input linear: h = x @ w + b (LDS-staged w, 4x4 register tile) ----
__global__ __launch_bounds__(256) void k_gemm(const float* __restrict__ x,
                                              const float* __restrict__ w,
                                              const float* __restrict__ bias,
                                              float* __restrict__ h) {
    __shared__ float wls[64][DD];   // 32 KiB (one k-chunk of w)
    __shared__ float xs[32][DD];    // 16 KiB
    int tid = threadIdx.x;
    int rbase = blockIdx.x * 32;
    int cg = tid & 31;              // col group (4 cols)
    int rg = tid >> 5;              // row group (4 rows)

#pragma unroll
    for (int p = 0; p < 4; ++p) {   // stage x tile: 32x128
        int i = p * 256 + tid;
        int r = i >> 5, c = (i & 31) * 4;
        *(float4*)&xs[r][c] = *(const float4*)&x[(size_t)(rbase + r) * DD + c];
    }

    float4 acc[4];
#pragma unroll
    for (int i = 0; i < 4; ++i) acc[i] = make_float4(0.f, 0.f, 0.f, 0.f);

    for (int chunk = 0; chunk < 2; ++chunk) {
        __syncthreads();
#pragma unroll
        for (int p = 0; p < 8; ++p) {   // stage w chunk: 64x128
            int i = p * 256 + tid;
            int kr = i >> 5, c = (i & 31) * 4;
            *(float4*)&wls[kr][c] = *(const float4*)&w[(size_t)(chunk * 64 + kr) * DD + c];
        }
        __syncthreads();
#pragma unroll 4
        for (int kk = 0; kk < 64; ++kk) {
            float4 wv = *(const float4*)&wls[kk][cg * 4];
            int k = chunk * 64 + kk;
#pragma unroll
            for (int i = 0; i < 4; ++i) {
                float xv = xs[rg * 4 + i][k];
                acc[i].x += xv * wv.x; acc[i].y += xv * wv.y;
                acc[i].z += xv * wv.z; acc[i].w += xv * wv.w;
            }
        }
    }

    float4 bv = *(const float4*)&bias[cg * 4];
#pragma unroll
    for (int i = 0; i < 4; ++i) {
        float4 o;
        o.x = acc[i].x + bv.x; o.y = acc[i].y + bv.y;
        o.z = acc[i].z + bv.z; o.w = acc[i].w + bv.w;
        *(float4*)&h[(size_t)(rbase + rg * 4 + i) * DD + cg * 4] = o;
    }
}

// ---------- merged layer: gather-conv + residual VQ + h update ----------
// Reads hin (gather, all rows), writes hout (own rows only) -> race-free via
// ping-pong. Per-dim gather chain: ascending j, one fma per term = bitwise
// identical to the split spmm's agg; a0/a1 stay in registers (fp32 store/load
// is bit-preserving, so values match the split version exactly). VQ code is
// byte-for-byte the R13-validated kernel.
__global__ __launch_bounds__(512) void k_layer(const float* __restrict__ hin,
                                               float* __restrict__ hout,
                                               const float* __restrict__ normf,
                                               const int* __restrict__ rs,
                                               const int* __restrict__ csr,
                                               const float* __restrict__ cbn_layer,
                                               float* __restrict__ idsf,
                                               float* __restrict__ lpart,
                                               int layer) {
    __shared__ float cb_s[LAYER_CBN];        // 24,960 B (permuted layout)
    __shared__ float resid_s[8][RBUF];       // padded resid (stride 36/slice)
    __shared__ float wsum[8];
    int tid = threadIdx.x;

    {   // linear copy: global cbn is already in the permuted layout
        const float4* src = (const float4*)cbn_layer;
        float4* dst = (float4*)cb_s;
        for (int t = tid; t < LAYER_CBN / 4; t += 512) dst[t] = src[t];
    }
    __syncthreads();

    int w = tid >> 6;      // wave id (0..7)
    int l = tid & 63;      // lane
    int off = 2 * l;       // this lane's dims: 2l, 2l+1
    int rwrd = (l >> 4) * RSTRIDE + ((2 * l) & 31);           // resid write word
    int sq = l & 3;                                            // resid read slice
    int cb2 = ((l >> 1) & 7) * ISTRIDE + (l >> 4) * 4 + 2 * (l & 1); // cb[?][2l] word
    float lsum = 0.f;

    for (int it = 0; it < ROWS_PER_FBLOCK / 8; ++it) {
        int r = blockIdx.x * ROWS_PER_FBLOCK + it * 8 + w;
        if (r < NN) {                        // wave-uniform guard (tail block)
            int s0 = rs[r], e0 = rs[r + 1];

            // --- gather: agg[r][off..off+1], ascending-j fma chain ---
            float a0 = 0.f, a1 = 0.f;
            int j = s0;
            for (; j + 8 <= e0; j += 8) {
                int c[8]; float n[8]; float2 v[8];
#pragma unroll
                for (int u = 0; u < 8; ++u) c[u] = csr[j + u];
#pragma unroll
                for (int u = 0; u < 8; ++u) n[u] = normf[c[u]];
#pragma unroll
                for (int u = 0; u < 8; ++u) v[u] = *(const float2*)&hin[(size_t)c[u] * DD + off];
#pragma unroll
                for (int u = 0; u < 8; ++u) { a0 += n[u] * v[u].x; a1 += n[u] * v[u].y; }
            }
            for (; j + 4 <= e0; j += 4) {
                int c[4]; float n[4]; float2 v[4];
#pragma unroll
                for (int u = 0; u < 4; ++u) c[u] = csr[j + u];
#pragma unroll
                for (int u = 0; u < 4; ++u) n[u] = normf[c[u]];
#pragma unroll
                for (int u = 0; u < 4; ++u) v[u] = *(const float2*)&hin[(size_t)c[u] * DD + off];
#pragma unroll
                for (int u = 0; u < 4; ++u) { a0 += n[u] * v[u].x; a1 += n[u] * v[u].y; }
            }
            for (; j < e0; ++j) {
                int c = csr[j];
                float ns = normf[c];
                float2 v = *(const float2*)&hin[(size_t)c * DD + off];
                a0 += ns * v.x;
                a1 += ns * v.y;
            }

            float nr = normf[r];
            float2 hv = *(const float2*)&hin[(size_t)r * DD + off];
            float x0 = nr * (a0 + nr * hv.x);
            float x1 = nr * (a1 + nr * hv.y);
            float r0 = x0, r1 = x1;

            // --- residual VQ (R13-validated, wave-private, barrier-free) ---
            for (int q = 0; q < NQ; ++q) {
                *(float2*)&resid_s[w][rwrd] = make_float2(r0, r1);
                // wave-synchronous: same-wave ds_write -> ds_read

                const float* cbq = &cb_s[q * QSTRIDE];
                const float* rsd = resid_s[w];
                float pd = 0.f;
#pragma unroll
                for (int i = 0; i < 8; ++i) {
                    float4 cv = *(const float4*)&cbq[i * ISTRIDE + l * 4];
                    float4 rv = *(const float4*)&rsd[sq * RSTRIDE + i * 4];
                    pd += cv.x * rv.x + cv.y * rv.y + cv.z * rv.z + cv.w * rv.w;
                }
                pd += __shfl_xor(pd, 1);
                pd += __shfl_xor(pd, 2);   // full dot(resid, cbn[kq]) in each quad

                float best = pd;
                int bk = l >> 2;
                for (int m = 4; m < 64; m <<= 1) {
                    float ov = __shfl_xor(best, m);
                    int oi = __shfl_xor(bk, m);
                    if (ov > best || (ov == best && oi < bk)) { best = ov; bk = oi; }
                }
                // bk = argmax (min index on tie), agreed by all lanes

                float2 cv2 = *(const float2*)&cb_s[q * QSTRIDE + bk * 16 + cb2];
                r0 -= cv2.x;
                r1 -= cv2.y;
                lsum += r0 * r0 + r1 * r1;

                if (l == 0) idsf[(size_t)r * (NL * NQ) + layer * NQ + q] = (float)bk;
            }

            *(float2*)&hout[(size_t)r * DD + off] = make_float2(x0 + hv.x, x1 + hv.y);
        }
    }

    // block loss partial (deterministic)
#pragma unroll
    for (int m = 1; m < 64; m <<= 1) lsum += __shfl_xor(lsum, m);
    if (l == 0) wsum[w] = lsum;
    __syncthreads();
    if (tid == 0) {
        float tot = 0.f;
#pragma unroll
        for (int i = 0; i < 8; ++i) tot += wsum[i];
        lpart[layer * FUSED_BLOCKS + blockIdx.x] = tot * (0.25f / (float)(NN * DD));
    }
}

__global__ __launch_bounds__(256) void k_loss_reduce(const float* __restrict__ part,
                                                     float* __restrict__ out_loss) {
    __shared__ float s[256];
    float a = 0.f;
    for (int i = threadIdx.x; i < LPART_COUNT; i += 256) a += part[i];
    s[threadIdx.x] = a;
    __syncthreads();
    for (int o = 128; o > 0; o >>= 1) {
        if (threadIdx.x < o) s[threadIdx.x] += s[threadIdx.x + o];
        __syncthreads();
    }
    if (threadIdx.x == 0) out_loss[0] = s[0];
}

extern "C" void kernel_launch(void* const* d_in, const int* in_sizes, int n_in,
                              void* d_out, int out_size, void* d_ws, size_t ws_size,
                              hipStream_t stream) {
    if (ws_size < WS_NEEDED) return;

    const float* x    = (const float*)d_in[0];
    const float* w_in = (const float*)d_in[1];
    const float* b_in = (const float*)d_in[2];
    const float* cbs  = (const float*)d_in[3];
    const int*   erow = (const int*)d_in[4];
    const int*   ecol = (const int*)d_in[5];

    float* out  = (float*)d_out;
    float* hout = out;                                   // [N][D] final h = output 0
    float* loss = out + (size_t)NN * DD;                 // scalar output 1
    float* idsf = out + (size_t)NN * DD + 1;             // [N][9] output 2 (as float)

    char* ws = (char*)d_ws;
    float* ha      = (float*)(ws + OFF_HA);              // ping-pong h buffer
    int*   csrf    = (int*)(ws + OFF_CSRF);              // aliases ha (dead before gemm)
    int*   cursorp = (int*)(ws + OFF_CURP);              // aliases ha (dead before gemm)
    int*   csr     = (int*)(ws + OFF_CSR);
    float* cbn     = (float*)(ws + OFF_CBN);
    float* normf   = (float*)(ws + OFF_NORM);
    int*   rs      = (int*)(ws + OFF_RS);
    int*   bsum    = (int*)(ws + OFF_BSUM);
    float* lpart   = (float*)(ws + OFF_LPART);

    // zero padded cursor (6.4 MB)
    hipMemsetAsync(ws + OFF_CURP, 0, 6400000, stream);

    const int NB_B  = (EE + EPB - 1) / EPB;  // 782 (batched fill)
    const int NB_SC = (NN + 1023) / 1024;    // 98
    const int NB_W  = (NN + 3) / 4;          // 25000 (4 waves/block)

    k_fill_fixed<<<NB_B, 256, 0, stream>>>(erow, ecol, cursorp, csrf);
    k_scan1<<<NB_SC, 1024, 0, stream>>>(cursorp, rs, bsum);
    k_scan2<<<1, 128, 0, stream>>>(bsum, NB_SC);
    k_scan3<<<NB_SC, 1024, 0, stream>>>(cursorp, rs, bsum, normf);
    k_sortcompact<<<NB_W, 256, 0, stream>>>(cursorp, rs, csrf, csr);

    k_cbnorm<<<NL * NQ * KK, 128, 0, stream>>>(cbs, cbn);

    // ping-pong: gemm -> ha; L0: ha -> out; L1: out -> ha; L2: ha -> out
    k_gemm<<<NN / 32, 256, 0, stream>>>(x, w_in, b_in, ha);

    k_layer<<<FUSED_BLOCKS, 512, 0, stream>>>(ha, hout, normf, rs, csr,
                                              cbn + (size_t)0 * LAYER_CBN,
                                              idsf, lpart, 0);
    k_layer<<<FUSED_BLOCKS, 512, 0, stream>>>(hout, ha, normf, rs, csr,
                                              cbn + (size_t)1 * LAYER_CBN,
                                              idsf, lpart, 1);
    k_layer<<<FUSED_BLOCKS, 512, 0, stream>>>(ha, hout, normf, rs, csr,
                                              cbn + (size_t)2 * LAYER_CBN,
                                              idsf, lpart, 2);

    k_loss_reduce<<<1, 256, 0, stream>>>(lpart, loss);
}